// Round 1
// baseline (830.865 us; speedup 1.0000x reference)
//
#include <hip/hip_runtime.h>

// VectorQuantizerEMA forward on MI355X (gfx950).
// Pipeline: memset(ws) -> k_esq (||e_j||^2) -> k_main (fused fp32 GEMM+argmin+
// quantize+loss+segment atomics) -> k_final (EMA update / normalize / loss).

#define N_ROWS 65536
#define DIM 128
#define NE 1024
#define BM 128
#define BN 128

// ws layout (float offsets)
#define WS_ESQ   0
#define WS_CNT   1024
#define WS_LOSS  2048
#define WS_ESUM  4096
#define WS_FLOATS (WS_ESUM + DIM*NE)

// out layout (float offsets), reference return order
#define O_Q    0
#define O_IND  (N_ROWS*DIM)
#define O_LOSS (O_IND + N_ROWS)
#define O_ENEW (O_LOSS + 1)
#define O_CS   (O_ENEW + DIM*NE)
#define O_EAVG (O_CS + NE)

__global__ void k_esq(const float* __restrict__ E, float* __restrict__ esq) {
    int j = blockIdx.x * 256 + threadIdx.x;   // coalesced across j
    float s = 0.f;
    #pragma unroll 8
    for (int d = 0; d < DIM; ++d) { float v = E[d*NE + j]; s += v*v; }
    esq[j] = s;
}

// 256 threads, block tile 128 rows x 128 cols per chunk, 8 chunks over 1024 codes.
// Thread (ty,tx) = (tid>>4, tid&15): rows ty*8..+7, cols chunk+tx*8..+7, 8x8 acc.
// LDS: xs[row][k] swizzled k^=((row>>3)&3)<<2 ; es_t[c][k] swizzled k^=((c>>3)&7)<<2
// -> fragment ds_read_b128 are bank-conflict-free (broadcast across the other dim).
__global__ __launch_bounds__(256) void k_main(
    const float* __restrict__ X, const float* __restrict__ E,
    float* __restrict__ ws, float* __restrict__ out) {
    __shared__ float xs[BM*DIM];   // 64 KiB
    __shared__ float es[BN*DIM];   // 64 KiB (reused as ind_sh/red after GEMM)

    const float* esq  = ws + WS_ESQ;
    float* cnt   = ws + WS_CNT;
    float* lossp = ws + WS_LOSS;
    float* esum  = ws + WS_ESUM;
    float* outQ  = out + O_Q;
    float* outI  = out + O_IND;

    const int tid = threadIdx.x;
    const int ty = tid >> 4, tx = tid & 15;
    const int rowBase = blockIdx.x * BM;

    // ---- stage X tile (coalesced float4, swizzled store) ----
    {
        const float4* Xg = (const float4*)(X + (size_t)rowBase * DIM);
        float4* xs4w = (float4*)xs;
        #pragma unroll
        for (int t = 0; t < 16; ++t) {
            int i = tid + t*256;           // float4 index in [0,4096)
            int row = i >> 5, k4 = i & 31;
            xs4w[row*32 + (k4 ^ ((row>>3)&3))] = Xg[i];
        }
    }

    float bd[8]; int bi[8];
    #pragma unroll
    for (int r = 0; r < 8; ++r) { bd[r] = 3.4e38f; bi[r] = 0; }

    const float4* xs4 = (const float4*)xs;
    const float4* es4 = (const float4*)es;
    const int xsw = ty & 3;   // == (row>>3)&3 for row = ty*8+r
    const int esw = tx & 7;   // == (c>>3)&7  for c   = tx*8+cc

    for (int cb = 0; cb < NE; cb += BN) {
        __syncthreads();   // previous chunk's es reads complete
        // ---- stage E chunk, transposed + swizzled ----
        #pragma unroll
        for (int t = 0; t < 16; ++t) {
            int i = tid + t*256;
            int k = i >> 5, c = (i & 31) << 2;
            float4 v = *(const float4*)(E + k*NE + cb + c);
            es[(c+0)*DIM + (k ^ ((((c+0)>>3)&7)<<2))] = v.x;
            es[(c+1)*DIM + (k ^ ((((c+1)>>3)&7)<<2))] = v.y;
            es[(c+2)*DIM + (k ^ ((((c+2)>>3)&7)<<2))] = v.z;
            es[(c+3)*DIM + (k ^ ((((c+3)>>3)&7)<<2))] = v.w;
        }
        __syncthreads();

        float acc[8][8];
        #pragma unroll
        for (int r = 0; r < 8; ++r)
            #pragma unroll
            for (int c = 0; c < 8; ++c) acc[r][c] = 0.f;

        for (int k4 = 0; k4 < 32; ++k4) {
            float4 xf[8], ef[8];
            #pragma unroll
            for (int r = 0; r < 8; ++r) xf[r] = xs4[(ty*8+r)*32 + (k4 ^ xsw)];
            #pragma unroll
            for (int c = 0; c < 8; ++c) ef[c] = es4[(tx*8+c)*32 + (k4 ^ esw)];
            #pragma unroll
            for (int r = 0; r < 8; ++r)
                #pragma unroll
                for (int c = 0; c < 8; ++c)
                    acc[r][c] += xf[r].x*ef[c].x + xf[r].y*ef[c].y
                               + xf[r].z*ef[c].z + xf[r].w*ef[c].w;
        }

        float4 q0 = *(const float4*)(esq + cb + tx*8);
        float4 q1 = *(const float4*)(esq + cb + tx*8 + 4);
        float eq[8] = {q0.x,q0.y,q0.z,q0.w,q1.x,q1.y,q1.z,q1.w};
        #pragma unroll
        for (int r = 0; r < 8; ++r)
            #pragma unroll
            for (int c = 0; c < 8; ++c) {
                float s = eq[c] - 2.f*acc[r][c];   // dist minus per-row const
                if (s < bd[r]) { bd[r] = s; bi[r] = cb + tx*8 + c; }  // first-min kept
            }
    }

    // ---- argmin reduce across the 16 tx lanes (index tie-break: smaller wins) ----
    #pragma unroll
    for (int r = 0; r < 8; ++r) {
        #pragma unroll
        for (int off = 8; off; off >>= 1) {
            float od = __shfl_down(bd[r], off, 16);
            int   oi = __shfl_down(bi[r], off, 16);
            if (od < bd[r] || (od == bd[r] && oi < bi[r])) { bd[r] = od; bi[r] = oi; }
        }
    }

    __syncthreads();   // all es reads done -> safe to overlay
    int*   ind_sh = (int*)es;
    float* red    = es + 256;
    if (tx == 0) {
        #pragma unroll
        for (int r = 0; r < 8; ++r) {
            int row = ty*8 + r;
            ind_sh[row] = bi[r];
            outI[rowBase + row] = (float)bi[r];
            atomicAdd(&cnt[bi[r]], 1.f);
        }
    }
    __syncthreads();

    // ---- quantize + straight-through + loss + embed_sum atomics ----
    float lp = 0.f;
    {
        int row = tid >> 1, half = tid & 1;
        int j = ind_sh[row];
        int rsw = (row>>3)&3;
        float4* oq = (float4*)(outQ + (size_t)(rowBase+row)*DIM + half*64);
        #pragma unroll
        for (int d4 = 0; d4 < 16; ++d4) {
            int k4 = half*16 + d4;
            float4 xv = xs4[row*32 + (k4 ^ rsw)];
            int d = k4*4;
            float4 qv;
            qv.x = E[(d+0)*NE + j];
            qv.y = E[(d+1)*NE + j];
            qv.z = E[(d+2)*NE + j];
            qv.w = E[(d+3)*NE + j];
            float4 st;   // inputs + (quantize - inputs), as the reference writes it
            st.x = xv.x + (qv.x - xv.x);
            st.y = xv.y + (qv.y - xv.y);
            st.z = xv.z + (qv.z - xv.z);
            st.w = xv.w + (qv.w - xv.w);
            oq[d4] = st;
            float dx;
            dx = qv.x - xv.x; lp += dx*dx;
            dx = qv.y - xv.y; lp += dx*dx;
            dx = qv.z - xv.z; lp += dx*dx;
            dx = qv.w - xv.w; lp += dx*dx;
            atomicAdd(&esum[(d+0)*NE + j], xv.x);
            atomicAdd(&esum[(d+1)*NE + j], xv.y);
            atomicAdd(&esum[(d+2)*NE + j], xv.z);
            atomicAdd(&esum[(d+3)*NE + j], xv.w);
        }
    }
    #pragma unroll
    for (int off = 32; off; off >>= 1) lp += __shfl_down(lp, off, 64);
    if ((tid & 63) == 0) red[tid >> 6] = lp;
    __syncthreads();
    if (tid == 0) atomicAdd(lossp, red[0] + red[1] + red[2] + red[3]);
}

__global__ __launch_bounds__(1024) void k_final(
    const float* __restrict__ CS, const float* __restrict__ EA,
    const float* __restrict__ ws, float* __restrict__ out) {
    __shared__ float red[16];
    __shared__ float nsh;
    int tid = threadIdx.x;   // tid == code index j
    float csn = CS[tid]*0.99f + 0.01f*ws[WS_CNT + tid];
    out[O_CS + tid] = csn;
    float s = csn;
    #pragma unroll
    for (int off = 32; off; off >>= 1) s += __shfl_down(s, off, 64);
    if ((tid & 63) == 0) red[tid >> 6] = s;
    __syncthreads();
    if (tid == 0) {
        float t = 0.f;
        for (int i = 0; i < 16; ++i) t += red[i];
        nsh = t;
        out[O_LOSS] = ws[WS_LOSS] * (1.0f/((float)N_ROWS*(float)DIM));
    }
    __syncthreads();
    float n = nsh;
    float cs = (csn + 1e-5f) / (n + (float)NE*1e-5f) * n;
    for (int d = 0; d < DIM; ++d) {
        int i = d*NE + tid;   // coalesced across tid
        float ean = EA[i]*0.99f + 0.01f*ws[WS_ESUM + i];
        out[O_EAVG + i] = ean;
        out[O_ENEW + i] = ean / cs;
    }
}

extern "C" void kernel_launch(void* const* d_in, const int* in_sizes, int n_in,
                              void* d_out, int out_size, void* d_ws, size_t ws_size,
                              hipStream_t stream) {
    const float* X  = (const float*)d_in[0];   // inputs  [16,64,64,128]
    const float* E  = (const float*)d_in[1];   // embed   [128,1024]
    const float* CS = (const float*)d_in[2];   // cluster_size [1024]
    const float* EA = (const float*)d_in[3];   // embed_avg    [128,1024]
    float* out = (float*)d_out;
    float* ws  = (float*)d_ws;

    hipMemsetAsync(d_ws, 0, (size_t)WS_FLOATS * sizeof(float), stream);
    k_esq  <<<dim3(NE/256),     dim3(256),  0, stream>>>(E, ws + WS_ESQ);
    k_main <<<dim3(N_ROWS/BM),  dim3(256),  0, stream>>>(X, E, ws, out);
    k_final<<<dim3(1),          dim3(1024), 0, stream>>>(CS, EA, ws, out);
}

// Round 2
// 634.380 us; speedup vs baseline: 1.3097x; 1.3097x over previous
//
#include <hip/hip_runtime.h>

// VectorQuantizerEMA forward on MI355X (gfx950).
// memset(ws) -> k_prep (bf16 hi/lo split of E, swizzled B-images + E^T + ||e||^2)
// -> k_main (MFMA bf16-split GEMM argmin + quantize + loss + segment atomics)
// -> k_final (EMA update / normalize).

#define N_ROWS 65536
#define DIM 128
#define NE 1024

typedef __attribute__((ext_vector_type(8))) short short8;
typedef __attribute__((ext_vector_type(4))) float f32x4;

// ws float offsets
#define WS_ESQ   0
#define WS_CNT   1024
#define WS_LOSS  2048
#define WS_ESUM  4096                  // [128][1024]
#define WS_EHI   135168                // 65536 floats = 256KB bf16 image (swizzled, chunked)
#define WS_ELO   200704                // 65536 floats
#define WS_ET    266240                // [1024][128] fp32 transposed embed
#define WS_FLOATS 397312
#define WS_ZERO_BYTES (135168*4)       // esq..esum zeroed (esq rewritten by prep)

// out float offsets (reference return order)
#define O_Q    0
#define O_IND  (N_ROWS*DIM)
#define O_LOSS (O_IND + N_ROWS)
#define O_ENEW (O_LOSS + 1)
#define O_CS   (O_ENEW + DIM*NE)
#define O_EAVG (O_CS + NE)

__device__ __forceinline__ unsigned short f2bf(float f) {
    unsigned u = __float_as_uint(f);
    unsigned r = (u + 0x7fffu + ((u >> 16) & 1u)) >> 16;
    return (unsigned short)r;
}
__device__ __forceinline__ float bf2f(unsigned short h) {
    return __uint_as_float(((unsigned)h) << 16);
}

// One thread per code: build swizzled bf16 hi/lo B-images (16 chunks of 64 codes,
// image byte = c*256 + ((k*2) ^ ((c&7)<<4))), E^T, and ||e||^2.
__global__ __launch_bounds__(256) void k_prep(const float* __restrict__ E,
                                              float* __restrict__ ws) {
    int code = blockIdx.x * 256 + threadIdx.x;
    unsigned short* ehi = (unsigned short*)(ws + WS_EHI);
    unsigned short* elo = (unsigned short*)(ws + WS_ELO);
    float* et = ws + WS_ET;
    int chunk = code >> 6, c = code & 63;
    int base = chunk * 8192 + c * 128;     // ushort index
    int sw = (c & 7) << 4;                 // byte swizzle
    float s = 0.f;
    for (int k = 0; k < DIM; ++k) {
        float v = E[k * NE + code];        // coalesced across threads
        s += v * v;
        unsigned short h = f2bf(v);
        unsigned short l = f2bf(v - bf2f(h));
        int boff = ((k * 2) ^ sw) >> 1;
        ehi[base + boff] = h;
        elo[base + boff] = l;
        et[code * DIM + k] = v;
    }
    ws[WS_ESQ + code] = s;
}

// 256 threads = 4 waves; BM=128 rows/block; codes in 16 chunks of 64 (LDS dbuf).
// Per wave: 32 rows (2 rowtiles of 16), A-frags (hi/lo) in registers for all K.
// dist_j = ||e_j||^2 - 2*x.e_j ; x.e via 3 MFMA passes hh+hl+lh (bf16 split).
__global__ __launch_bounds__(256, 2) void k_main(const float* __restrict__ X,
                                                 float* __restrict__ ws,
                                                 float* __restrict__ out) {
    __shared__ __align__(16) char es[2][32768];   // [buf][ hi 16KB | lo 16KB ]
    __shared__ __align__(16) float esq_lds[NE];
    __shared__ int ind_sh[128];
    __shared__ float red2[4];

    const int tid = threadIdx.x;
    const int lane = tid & 63;
    const int wid = tid >> 6;
    const int g = lane >> 4;          // k-group (0..3)
    const int cl = lane & 15;         // row/col within 16-tile
    const int rowBase = blockIdx.x * 128;

    // stage ||e||^2 into LDS
    ((float4*)esq_lds)[tid] = ((const float4*)(ws + WS_ESQ))[tid];

    // ---- load + split A fragments (held in registers for the whole kernel) ----
    // A layout (16x16x32): row = lane&15, k = (lane>>4)*8 + e
    short8 ah[2][4], al[2][4];
    #pragma unroll
    for (int rt = 0; rt < 2; ++rt) {
        int row = rowBase + wid * 32 + rt * 16 + cl;
        const float* xr = X + (size_t)row * DIM + g * 8;
        #pragma unroll
        for (int kt = 0; kt < 4; ++kt) {
            float4 a = *(const float4*)(xr + kt * 32);
            float4 b = *(const float4*)(xr + kt * 32 + 4);
            float xv[8] = {a.x, a.y, a.z, a.w, b.x, b.y, b.z, b.w};
            short8 h, l;
            #pragma unroll
            for (int e = 0; e < 8; ++e) {
                unsigned short hh = f2bf(xv[e]);
                h[e] = (short)hh;
                l[e] = (short)f2bf(xv[e] - bf2f(hh));
            }
            ah[rt][kt] = h;
            al[rt][kt] = l;
        }
    }

    const float4* ehi4 = (const float4*)(ws + WS_EHI);
    const float4* elo4 = (const float4*)(ws + WS_ELO);

    // stage chunk 0
    #pragma unroll
    for (int t = 0; t < 4; ++t) {
        int i = tid + t * 256;
        *(float4*)(&es[0][i * 16]) = ehi4[i];
        *(float4*)(&es[0][16384 + i * 16]) = elo4[i];
    }
    __syncthreads();

    float bd[8];
    int bi[8];
    #pragma unroll
    for (int s = 0; s < 8; ++s) { bd[s] = 1e30f; bi[s] = 0; }

    const int swB = (cl & 7) << 4;

    for (int c = 0; c < 16; ++c) {
        const int cur = c & 1;
        // T14: issue next chunk's global loads before compute
        float4 sh[4], sl[4];
        if (c < 15) {
            #pragma unroll
            for (int t = 0; t < 4; ++t) {
                int i = tid + t * 256;
                sh[t] = ehi4[(c + 1) * 1024 + i];
                sl[t] = elo4[(c + 1) * 1024 + i];
            }
        }

        f32x4 acc[2][4];
        #pragma unroll
        for (int rt = 0; rt < 2; ++rt)
            #pragma unroll
            for (int ct = 0; ct < 4; ++ct) acc[rt][ct] = (f32x4){0.f, 0.f, 0.f, 0.f};

        const char* hb = es[cur];
        #pragma unroll
        for (int kt = 0; kt < 4; ++kt) {
            short8 bh[4], bl[4];
            #pragma unroll
            for (int ct = 0; ct < 4; ++ct) {
                int cc = ct * 16 + cl;                       // code within chunk
                int off = cc * 256 + ((kt * 64 + g * 16) ^ swB);
                bh[ct] = *(const short8*)(hb + off);
                bl[ct] = *(const short8*)(hb + 16384 + off);
            }
            #pragma unroll
            for (int ct = 0; ct < 4; ++ct)
                #pragma unroll
                for (int rt = 0; rt < 2; ++rt) {
                    f32x4 t = acc[rt][ct];
                    t = __builtin_amdgcn_mfma_f32_16x16x32_bf16(ah[rt][kt], bl[ct], t, 0, 0, 0);
                    t = __builtin_amdgcn_mfma_f32_16x16x32_bf16(al[rt][kt], bh[ct], t, 0, 0, 0);
                    t = __builtin_amdgcn_mfma_f32_16x16x32_bf16(ah[rt][kt], bh[ct], t, 0, 0, 0);
                    acc[rt][ct] = t;
                }
        }

        // dist + running argmin. C layout: row=(lane>>4)*4+r, col=lane&15
        #pragma unroll
        for (int ct = 0; ct < 4; ++ct) {
            int code = c * 64 + ct * 16 + cl;
            float eqv = esq_lds[code];
            #pragma unroll
            for (int rt = 0; rt < 2; ++rt)
                #pragma unroll
                for (int r = 0; r < 4; ++r) {
                    float s = eqv - 2.f * acc[rt][ct][r];
                    int sl_ = rt * 4 + r;
                    if (s < bd[sl_]) { bd[sl_] = s; bi[sl_] = code; }
                }
        }

        if (c < 15) {
            #pragma unroll
            for (int t = 0; t < 4; ++t) {
                int i = tid + t * 256;
                *(float4*)(&es[cur ^ 1][i * 16]) = sh[t];
                *(float4*)(&es[cur ^ 1][16384 + i * 16]) = sl[t];
            }
        }
        __syncthreads();
    }

    // ---- argmin across the 16 col-lanes (tie-break: smaller index) ----
    #pragma unroll
    for (int s = 0; s < 8; ++s) {
        #pragma unroll
        for (int off = 1; off < 16; off <<= 1) {
            float od = __shfl_xor(bd[s], off, 16);
            int oi = __shfl_xor(bi[s], off, 16);
            if (od < bd[s] || (od == bd[s] && oi < bi[s])) { bd[s] = od; bi[s] = oi; }
        }
    }
    if (cl == 0) {
        #pragma unroll
        for (int rt = 0; rt < 2; ++rt)
            #pragma unroll
            for (int r = 0; r < 4; ++r) {
                int row = wid * 32 + rt * 16 + g * 4 + r;
                int b = bi[rt * 4 + r];
                ind_sh[row] = b;
                out[O_IND + rowBase + row] = (float)b;
                atomicAdd(ws + WS_CNT + b, 1.f);
            }
    }
    __syncthreads();

    // ---- quantize + straight-through + loss + embed_sum atomics ----
    float lp = 0.f;
    {
        int row = tid >> 1, half = tid & 1;
        int j = ind_sh[row];
        const float4* xr = (const float4*)(X + (size_t)(rowBase + row) * DIM + half * 64);
        const float4* er = (const float4*)(ws + WS_ET + j * DIM + half * 64);
        float4* oq = (float4*)(out + O_Q + (size_t)(rowBase + row) * DIM + half * 64);
        float* esum = ws + WS_ESUM;
        #pragma unroll
        for (int t = 0; t < 16; ++t) {
            float4 xv = xr[t];
            float4 qv = er[t];
            float4 st;
            st.x = xv.x + (qv.x - xv.x);
            st.y = xv.y + (qv.y - xv.y);
            st.z = xv.z + (qv.z - xv.z);
            st.w = xv.w + (qv.w - xv.w);
            oq[t] = st;
            float dx;
            dx = qv.x - xv.x; lp += dx * dx;
            dx = qv.y - xv.y; lp += dx * dx;
            dx = qv.z - xv.z; lp += dx * dx;
            dx = qv.w - xv.w; lp += dx * dx;
            int d = half * 64 + t * 4;
            atomicAdd(&esum[(d + 0) * NE + j], xv.x);
            atomicAdd(&esum[(d + 1) * NE + j], xv.y);
            atomicAdd(&esum[(d + 2) * NE + j], xv.z);
            atomicAdd(&esum[(d + 3) * NE + j], xv.w);
        }
    }
    #pragma unroll
    for (int off = 32; off; off >>= 1) lp += __shfl_down(lp, off, 64);
    if (lane == 0) red2[wid] = lp;
    __syncthreads();
    if (tid == 0) atomicAdd(ws + WS_LOSS, red2[0] + red2[1] + red2[2] + red2[3]);
}

__global__ __launch_bounds__(1024) void k_final(const float* __restrict__ CS,
                                                const float* __restrict__ EA,
                                                const float* __restrict__ ws,
                                                float* __restrict__ out) {
    __shared__ float red[16];
    __shared__ float nsh;
    int tid = threadIdx.x;   // tid == code index j
    float csn = CS[tid] * 0.99f + 0.01f * ws[WS_CNT + tid];
    out[O_CS + tid] = csn;
    float s = csn;
    #pragma unroll
    for (int off = 32; off; off >>= 1) s += __shfl_down(s, off, 64);
    if ((tid & 63) == 0) red[tid >> 6] = s;
    __syncthreads();
    if (tid == 0) {
        float t = 0.f;
        for (int i = 0; i < 16; ++i) t += red[i];
        nsh = t;
        out[O_LOSS] = ws[WS_LOSS] * (1.0f / ((float)N_ROWS * (float)DIM));
    }
    __syncthreads();
    float n = nsh;
    float cs = (csn + 1e-5f) / (n + (float)NE * 1e-5f) * n;
    for (int d = 0; d < DIM; ++d) {
        int i = d * NE + tid;
        float ean = EA[i] * 0.99f + 0.01f * ws[WS_ESUM + i];
        out[O_EAVG + i] = ean;
        out[O_ENEW + i] = ean / cs;
    }
}

extern "C" void kernel_launch(void* const* d_in, const int* in_sizes, int n_in,
                              void* d_out, int out_size, void* d_ws, size_t ws_size,
                              hipStream_t stream) {
    const float* X = (const float*)d_in[0];    // inputs  [16,64,64,128]
    const float* E = (const float*)d_in[1];    // embed   [128,1024]
    const float* CS = (const float*)d_in[2];   // cluster_size [1024]
    const float* EA = (const float*)d_in[3];   // embed_avg    [128,1024]
    float* out = (float*)d_out;
    float* ws = (float*)d_ws;

    hipMemsetAsync(d_ws, 0, (size_t)WS_ZERO_BYTES, stream);
    k_prep<<<dim3(NE / 256), dim3(256), 0, stream>>>(E, ws);
    k_main<<<dim3(N_ROWS / 128), dim3(256), 0, stream>>>(X, ws, out);
    k_final<<<dim3(1), dim3(1024), 0, stream>>>(CS, EA, ws, out);
}

// Round 3
// 452.775 us; speedup vs baseline: 1.8351x; 1.4011x over previous
//
#include <hip/hip_runtime.h>

// VectorQuantizerEMA forward on MI355X (gfx950).
// memset(10KB) -> k_prep (bf16 hi/lo split of E, swizzled B-images + E^T + ||e||^2)
// -> k_main (MFMA bf16-split GEMM argmin + quantize + loss; 1 int atomic/row for cnt)
// -> k_scan (prefix-sum of cnt -> bucket offsets) -> k_scatter (row -> bucket)
// -> k_segsum (per-code gather-sum, atomic-free) -> k_final (EMA update).

#define N_ROWS 65536
#define DIM 128
#define NE 1024

typedef __attribute__((ext_vector_type(8))) short short8;
typedef __attribute__((ext_vector_type(4))) float f32x4;

// ws float offsets
#define WS_ESQ    0
#define WS_CNTI   1024                 // 1024 ints (counts, also k_final)
#define WS_LOSS   2048
#define WS_ESUMT  4096                 // [1024 codes][128 dims] fp32
#define WS_EHI    135168               // 65536 f: bf16 hi image (dead after k_main)
#define WS_ELO    200704               // 65536 f: bf16 lo image (dead after k_main)
#define WS_ET     266240               // [1024][128] fp32 transposed embed
#define WS_FLOATS 397312
// overlays (only touched after k_main completes)
#define WS_BUCKET WS_EHI               // 65536 ints: row ids grouped by code
#define WS_OFF    WS_ELO               // 1024 ints: exclusive prefix of cnt
#define WS_POS    (WS_ELO + 1024)      // 1024 ints: scatter cursors
#define WS_ZERO_BYTES (2560 * 4)       // esq+cnt+loss region

// out float offsets (reference return order)
#define O_Q    0
#define O_IND  (N_ROWS*DIM)
#define O_LOSS (O_IND + N_ROWS)
#define O_ENEW (O_LOSS + 1)
#define O_CS   (O_ENEW + DIM*NE)
#define O_EAVG (O_CS + NE)

__device__ __forceinline__ unsigned short f2bf(float f) {
    unsigned u = __float_as_uint(f);
    unsigned r = (u + 0x7fffu + ((u >> 16) & 1u)) >> 16;
    return (unsigned short)r;
}
__device__ __forceinline__ float bf2f(unsigned short h) {
    return __uint_as_float(((unsigned)h) << 16);
}

// One thread per code: swizzled bf16 hi/lo B-images (16 chunks of 64 codes,
// image byte = c*256 + ((k*2) ^ ((c&7)<<4))), E^T, and ||e||^2.
__global__ __launch_bounds__(256) void k_prep(const float* __restrict__ E,
                                              float* __restrict__ ws) {
    int code = blockIdx.x * 256 + threadIdx.x;
    unsigned short* ehi = (unsigned short*)(ws + WS_EHI);
    unsigned short* elo = (unsigned short*)(ws + WS_ELO);
    float* et = ws + WS_ET;
    int chunk = code >> 6, c = code & 63;
    int base = chunk * 8192 + c * 128;     // ushort index
    int sw = (c & 7) << 4;                 // byte swizzle
    float s = 0.f;
    for (int k = 0; k < DIM; ++k) {
        float v = E[k * NE + code];        // coalesced across threads
        s += v * v;
        unsigned short h = f2bf(v);
        unsigned short l = f2bf(v - bf2f(h));
        int boff = ((k * 2) ^ sw) >> 1;
        ehi[base + boff] = h;
        elo[base + boff] = l;
        et[code * DIM + k] = v;
    }
    ws[WS_ESQ + code] = s;
}

// 256 threads = 4 waves; BM=128 rows/block; codes in 16 chunks of 64 (LDS dbuf).
// dist_j = ||e_j||^2 - 2*x.e_j ; x.e via 3 MFMA passes hh+hl+lh (bf16 split).
__global__ __launch_bounds__(256, 2) void k_main(const float* __restrict__ X,
                                                 float* __restrict__ ws,
                                                 float* __restrict__ out) {
    __shared__ __align__(16) char es[2][32768];   // [buf][ hi 16KB | lo 16KB ]
    __shared__ __align__(16) float esq_lds[NE];
    __shared__ int ind_sh[128];
    __shared__ float red2[4];

    const int tid = threadIdx.x;
    const int lane = tid & 63;
    const int wid = tid >> 6;
    const int g = lane >> 4;          // k-group (0..3)
    const int cl = lane & 15;         // row/col within 16-tile
    const int rowBase = blockIdx.x * 128;

    ((float4*)esq_lds)[tid] = ((const float4*)(ws + WS_ESQ))[tid];

    // ---- load + split A fragments (held in registers for the whole kernel) ----
    short8 ah[2][4], al[2][4];
    #pragma unroll
    for (int rt = 0; rt < 2; ++rt) {
        int row = rowBase + wid * 32 + rt * 16 + cl;
        const float* xr = X + (size_t)row * DIM + g * 8;
        #pragma unroll
        for (int kt = 0; kt < 4; ++kt) {
            float4 a = *(const float4*)(xr + kt * 32);
            float4 b = *(const float4*)(xr + kt * 32 + 4);
            float xv[8] = {a.x, a.y, a.z, a.w, b.x, b.y, b.z, b.w};
            short8 h, l;
            #pragma unroll
            for (int e = 0; e < 8; ++e) {
                unsigned short hh = f2bf(xv[e]);
                h[e] = (short)hh;
                l[e] = (short)f2bf(xv[e] - bf2f(hh));
            }
            ah[rt][kt] = h;
            al[rt][kt] = l;
        }
    }

    const float4* ehi4 = (const float4*)(ws + WS_EHI);
    const float4* elo4 = (const float4*)(ws + WS_ELO);

    #pragma unroll
    for (int t = 0; t < 4; ++t) {
        int i = tid + t * 256;
        *(float4*)(&es[0][i * 16]) = ehi4[i];
        *(float4*)(&es[0][16384 + i * 16]) = elo4[i];
    }
    __syncthreads();

    float bd[8];
    int bi[8];
    #pragma unroll
    for (int s = 0; s < 8; ++s) { bd[s] = 1e30f; bi[s] = 0; }

    const int swB = (cl & 7) << 4;

    for (int c = 0; c < 16; ++c) {
        const int cur = c & 1;
        float4 sh[4], sl[4];
        if (c < 15) {
            #pragma unroll
            for (int t = 0; t < 4; ++t) {
                int i = tid + t * 256;
                sh[t] = ehi4[(c + 1) * 1024 + i];
                sl[t] = elo4[(c + 1) * 1024 + i];
            }
        }

        f32x4 acc[2][4];
        #pragma unroll
        for (int rt = 0; rt < 2; ++rt)
            #pragma unroll
            for (int ct = 0; ct < 4; ++ct) acc[rt][ct] = (f32x4){0.f, 0.f, 0.f, 0.f};

        const char* hb = es[cur];
        #pragma unroll
        for (int kt = 0; kt < 4; ++kt) {
            short8 bh[4], bl[4];
            #pragma unroll
            for (int ct = 0; ct < 4; ++ct) {
                int cc = ct * 16 + cl;
                int off = cc * 256 + ((kt * 64 + g * 16) ^ swB);
                bh[ct] = *(const short8*)(hb + off);
                bl[ct] = *(const short8*)(hb + 16384 + off);
            }
            #pragma unroll
            for (int ct = 0; ct < 4; ++ct)
                #pragma unroll
                for (int rt = 0; rt < 2; ++rt) {
                    f32x4 t = acc[rt][ct];
                    t = __builtin_amdgcn_mfma_f32_16x16x32_bf16(ah[rt][kt], bl[ct], t, 0, 0, 0);
                    t = __builtin_amdgcn_mfma_f32_16x16x32_bf16(al[rt][kt], bh[ct], t, 0, 0, 0);
                    t = __builtin_amdgcn_mfma_f32_16x16x32_bf16(ah[rt][kt], bh[ct], t, 0, 0, 0);
                    acc[rt][ct] = t;
                }
        }

        // dist + running argmin. C layout: row=(lane>>4)*4+r, col=lane&15
        #pragma unroll
        for (int ct = 0; ct < 4; ++ct) {
            int code = c * 64 + ct * 16 + cl;
            float eqv = esq_lds[code];
            #pragma unroll
            for (int rt = 0; rt < 2; ++rt)
                #pragma unroll
                for (int r = 0; r < 4; ++r) {
                    float s = eqv - 2.f * acc[rt][ct][r];
                    int sl_ = rt * 4 + r;
                    if (s < bd[sl_]) { bd[sl_] = s; bi[sl_] = code; }
                }
        }

        if (c < 15) {
            #pragma unroll
            for (int t = 0; t < 4; ++t) {
                int i = tid + t * 256;
                *(float4*)(&es[cur ^ 1][i * 16]) = sh[t];
                *(float4*)(&es[cur ^ 1][16384 + i * 16]) = sl[t];
            }
        }
        __syncthreads();
    }

    // ---- argmin across the 16 col-lanes (tie-break: smaller index) ----
    #pragma unroll
    for (int s = 0; s < 8; ++s) {
        #pragma unroll
        for (int off = 1; off < 16; off <<= 1) {
            float od = __shfl_xor(bd[s], off, 16);
            int oi = __shfl_xor(bi[s], off, 16);
            if (od < bd[s] || (od == bd[s] && oi < bi[s])) { bd[s] = od; bi[s] = oi; }
        }
    }
    if (cl == 0) {
        int* cnt = (int*)(ws + WS_CNTI);
        #pragma unroll
        for (int rt = 0; rt < 2; ++rt)
            #pragma unroll
            for (int r = 0; r < 4; ++r) {
                int row = wid * 32 + rt * 16 + g * 4 + r;
                int b = bi[rt * 4 + r];
                ind_sh[row] = b;
                out[O_IND + rowBase + row] = (float)b;
                atomicAdd(&cnt[b], 1);
            }
    }
    __syncthreads();

    // ---- quantize + straight-through + loss (no esum atomics) ----
    float lp = 0.f;
    {
        int row = tid >> 1, half = tid & 1;
        int j = ind_sh[row];
        const float4* xr = (const float4*)(X + (size_t)(rowBase + row) * DIM + half * 64);
        const float4* er = (const float4*)(ws + WS_ET + j * DIM + half * 64);
        float4* oq = (float4*)(out + O_Q + (size_t)(rowBase + row) * DIM + half * 64);
        #pragma unroll
        for (int t = 0; t < 16; ++t) {
            float4 xv = xr[t];
            float4 qv = er[t];
            float4 st;
            st.x = xv.x + (qv.x - xv.x);
            st.y = xv.y + (qv.y - xv.y);
            st.z = xv.z + (qv.z - xv.z);
            st.w = xv.w + (qv.w - xv.w);
            oq[t] = st;
            float dx;
            dx = qv.x - xv.x; lp += dx * dx;
            dx = qv.y - xv.y; lp += dx * dx;
            dx = qv.z - xv.z; lp += dx * dx;
            dx = qv.w - xv.w; lp += dx * dx;
        }
    }
    #pragma unroll
    for (int off = 32; off; off >>= 1) lp += __shfl_down(lp, off, 64);
    if (lane == 0) red2[wid] = lp;
    __syncthreads();
    if (tid == 0) atomicAdd(ws + WS_LOSS, red2[0] + red2[1] + red2[2] + red2[3]);
}

// 1 block, 1024 threads: off = exclusive_scan(cnt); pos = 0.
__global__ __launch_bounds__(1024) void k_scan(float* __restrict__ ws) {
    __shared__ int wsum[16];
    int tid = threadIdx.x;
    int* cnt = (int*)(ws + WS_CNTI);
    int* off = (int*)(ws + WS_OFF);
    int* pos = (int*)(ws + WS_POS);
    int v = cnt[tid];
    int s = v;
    #pragma unroll
    for (int d = 1; d < 64; d <<= 1) {
        int t = __shfl_up(s, d, 64);
        if ((tid & 63) >= d) s += t;
    }
    if ((tid & 63) == 63) wsum[tid >> 6] = s;
    __syncthreads();
    if (tid == 0) {
        int run = 0;
        for (int w = 0; w < 16; ++w) { int t = wsum[w]; wsum[w] = run; run += t; }
    }
    __syncthreads();
    off[tid] = s - v + wsum[tid >> 6];
    pos[tid] = 0;
}

// one thread per row: claim slot, write row id into its code's bucket.
__global__ __launch_bounds__(256) void k_scatter(const float* __restrict__ out,
                                                 float* __restrict__ ws) {
    int i = blockIdx.x * 256 + threadIdx.x;
    int j = (int)out[O_IND + i];
    int* off = (int*)(ws + WS_OFF);
    int* pos = (int*)(ws + WS_POS);
    int* bucket = (int*)(ws + WS_BUCKET);
    int slot = atomicAdd(&pos[j], 1);
    bucket[off[j] + slot] = i;
}

// one block per code, 128 threads (thread d): sum assigned rows, write esumT[j][d].
__global__ __launch_bounds__(128) void k_segsum(const float* __restrict__ X,
                                                float* __restrict__ ws) {
    __shared__ int rs[256];
    int j = blockIdx.x, d = threadIdx.x;
    int* off = (int*)(ws + WS_OFF);
    int* cnt = (int*)(ws + WS_CNTI);
    int* bucket = (int*)(ws + WS_BUCKET);
    int o = off[j], n = cnt[j];
    float s = 0.f;
    for (int base = 0; base < n; base += 256) {
        int m = min(256, n - base);
        __syncthreads();
        if (d < m) rs[d] = bucket[o + base + d];
        if (d + 128 < m) rs[d + 128] = bucket[o + base + d + 128];
        __syncthreads();
        for (int i = 0; i < m; ++i) s += X[(size_t)rs[i] * DIM + d];
    }
    ws[WS_ESUMT + j * DIM + d] = s;
}

__global__ __launch_bounds__(1024) void k_final(const float* __restrict__ CS,
                                                const float* __restrict__ EA,
                                                const float* __restrict__ ws,
                                                float* __restrict__ out) {
    __shared__ float red[16];
    __shared__ float nsh;
    int tid = threadIdx.x;   // tid == code index j
    float csn = CS[tid] * 0.99f + 0.01f * (float)((const int*)(ws + WS_CNTI))[tid];
    out[O_CS + tid] = csn;
    float s = csn;
    #pragma unroll
    for (int off = 32; off; off >>= 1) s += __shfl_down(s, off, 64);
    if ((tid & 63) == 0) red[tid >> 6] = s;
    __syncthreads();
    if (tid == 0) {
        float t = 0.f;
        for (int i = 0; i < 16; ++i) t += red[i];
        nsh = t;
        out[O_LOSS] = ws[WS_LOSS] * (1.0f / ((float)N_ROWS * (float)DIM));
    }
    __syncthreads();
    float n = nsh;
    float cs = (csn + 1e-5f) / (n + (float)NE * 1e-5f) * n;
    for (int d = 0; d < DIM; ++d) {
        int i = d * NE + tid;
        float ean = EA[i] * 0.99f + 0.01f * ws[WS_ESUMT + tid * DIM + d];
        out[O_EAVG + i] = ean;
        out[O_ENEW + i] = ean / cs;
    }
}

extern "C" void kernel_launch(void* const* d_in, const int* in_sizes, int n_in,
                              void* d_out, int out_size, void* d_ws, size_t ws_size,
                              hipStream_t stream) {
    const float* X = (const float*)d_in[0];    // inputs  [16,64,64,128]
    const float* E = (const float*)d_in[1];    // embed   [128,1024]
    const float* CS = (const float*)d_in[2];   // cluster_size [1024]
    const float* EA = (const float*)d_in[3];   // embed_avg    [128,1024]
    float* out = (float*)d_out;
    float* ws = (float*)d_ws;

    hipMemsetAsync(d_ws, 0, (size_t)WS_ZERO_BYTES, stream);
    k_prep   <<<dim3(NE / 256),     dim3(256),  0, stream>>>(E, ws);
    k_main   <<<dim3(N_ROWS / 128), dim3(256),  0, stream>>>(X, ws, out);
    k_scan   <<<dim3(1),            dim3(1024), 0, stream>>>(ws);
    k_scatter<<<dim3(N_ROWS / 256), dim3(256),  0, stream>>>(out, ws);
    k_segsum <<<dim3(NE),           dim3(128),  0, stream>>>(X, ws);
    k_final  <<<dim3(1),            dim3(1024), 0, stream>>>(CS, EA, ws, out);
}

// Round 4
// 297.379 us; speedup vs baseline: 2.7940x; 1.5226x over previous
//
#include <hip/hip_runtime.h>

// VectorQuantizerEMA forward on MI355X (gfx950).
// memset(10KB) -> k_prep (bf16 hi/lo split of E into swizzled 32x32x16-MFMA
// B-images + E^T + ||e||^2; LDS-transposed, coalesced) -> k_main (32x32x16
// bf16-split MFMA argmin + coalesced quantize/ST/loss; 1 int atomic/row)
// -> k_scan (prefix-sum, n, cluster_size_new, loss) -> k_scatter (row->bucket)
// -> k_segsum (per-code gather-sum fused with EMA/normalize epilogue).

#define N_ROWS 65536
#define DIM 128
#define NE 1024

typedef __attribute__((ext_vector_type(8))) short short8;
typedef __attribute__((ext_vector_type(16))) float f32x16;

// ws float offsets
#define WS_ESQ    0
#define WS_CNTI   1024                  // 1024 ints
#define WS_LOSS   2048
#define WS_N      2049
#define WS_EHI    4096                  // 256KB bf16-hi image (16 chunks x 16KB)
#define WS_ELO    (WS_EHI + 65536)      // 256KB bf16-lo image
#define WS_ET     (WS_ELO + 65536)      // [1024][128] fp32 transposed embed
#define WS_BUCKET (WS_ET + DIM*NE)      // 65536 ints: row ids grouped by code
#define WS_OFF    (WS_BUCKET + 65536)   // 1024 ints
#define WS_POS    (WS_OFF + 1024)       // 1024 ints
#define WS_ZERO_BYTES (2560 * 4)

// out float offsets (reference return order)
#define O_Q    0
#define O_IND  (N_ROWS*DIM)
#define O_LOSS (O_IND + N_ROWS)
#define O_ENEW (O_LOSS + 1)
#define O_CS   (O_ENEW + DIM*NE)
#define O_EAVG (O_CS + NE)

__device__ __forceinline__ unsigned short f2bf(float f) {
    unsigned u = __float_as_uint(f);
    unsigned r = (u + 0x7fffu + ((u >> 16) & 1u)) >> 16;
    return (unsigned short)r;
}
__device__ __forceinline__ float bf2f(unsigned short h) {
    return __uint_as_float(((unsigned)h) << 16);
}
__device__ __forceinline__ void stage16(const void* g, void* l) {
    __builtin_amdgcn_global_load_lds(
        (const __attribute__((address_space(1))) unsigned*)g,
        (__attribute__((address_space(3))) unsigned*)l, 16, 0, 0);
}

// Image layout (per 64-code chunk, 16KB): byte = c*256 + ((k*2) ^ ((c&15)<<4)).
// Block b = chunk b. LDS transpose so global reads AND writes are coalesced.
__global__ __launch_bounds__(256) void k_prep(const float* __restrict__ E,
                                              float* __restrict__ ws) {
    __shared__ float ls[64 * 129];      // [c][k], pad 129 vs bank conflicts
    __shared__ float part[4][64];
    const int tid = threadIdx.x, b = blockIdx.x;
    const int lane = tid & 63, wid = tid >> 6;

    float sq = 0.f;
    #pragma unroll
    for (int t = 0; t < 32; ++t) {      // k = 4t + wid, c = lane (coalesced 256B)
        int k = t * 4 + wid;
        float v = E[k * NE + b * 64 + lane];
        ls[lane * 129 + k] = v;
        sq += v * v;
    }
    part[wid][lane] = sq;
    __syncthreads();
    if (tid < 64)
        ws[WS_ESQ + b * 64 + tid] =
            part[0][tid] + part[1][tid] + part[2][tid] + part[3][tid];

    char* ehiB = (char*)(ws + WS_EHI);
    char* eloB = (char*)(ws + WS_ELO);
    #pragma unroll
    for (int t = 0; t < 4; ++t) {       // 1024 16B-blocks per image
        int i = tid + t * 256;
        int c = i >> 4, slot = i & 15;
        int k0 = (slot ^ (c & 15)) * 8;
        short8 hv, lv;
        #pragma unroll
        for (int e = 0; e < 8; ++e) {
            float v = ls[c * 129 + k0 + e];
            unsigned short h = f2bf(v);
            hv[e] = (short)h;
            lv[e] = (short)f2bf(v - bf2f(h));
        }
        *(short8*)(ehiB + (size_t)b * 16384 + i * 16) = hv;
        *(short8*)(eloB + (size_t)b * 16384 + i * 16) = lv;
    }
    float* et = ws + WS_ET;
    #pragma unroll
    for (int t = 0; t < 8; ++t) {       // 2048 float4 per chunk
        int i = tid + t * 256;
        int c = i >> 5, k4 = (i & 31) * 4;
        float4 v;
        v.x = ls[c * 129 + k4 + 0];
        v.y = ls[c * 129 + k4 + 1];
        v.z = ls[c * 129 + k4 + 2];
        v.w = ls[c * 129 + k4 + 3];
        *(float4*)(et + (size_t)(b * 64 + c) * DIM + k4) = v;
    }
}

// 256 threads = 4 waves; 128 rows/block (wave: 32 rows); 16 chunks of 64 codes.
// dist_j = ||e_j||^2 - 2*x.e_j via 3-pass bf16-split 32x32x16 MFMA.
__global__ __launch_bounds__(256, 2) void k_main(const float* __restrict__ X,
                                                 float* __restrict__ ws,
                                                 float* __restrict__ out) {
    __shared__ __align__(16) char es[2][32768];   // [buf][ hi 16KB | lo 16KB ]
    __shared__ __align__(16) float esq_lds[NE];
    __shared__ int ind_sh[128];
    __shared__ float red2[4];

    const int tid = threadIdx.x;
    const int lane = tid & 63;
    const int wid = tid >> 6;
    const int col0 = lane & 31;
    const int hi = lane >> 5;
    const int rowBase = blockIdx.x * 128;

    const char* ehiB = (const char*)(ws + WS_EHI);
    const char* eloB = (const char*)(ws + WS_ELO);

    // stage chunk 0 (async DMA) before A-frag work
    #pragma unroll
    for (int t = 0; t < 4; ++t) {
        int i = tid + t * 256;
        stage16(ehiB + i * 16, &es[0][i * 16]);
        stage16(eloB + i * 16, &es[0][16384 + i * 16]);
    }

    ((float4*)esq_lds)[tid] = ((const float4*)(ws + WS_ESQ))[tid];

    // ---- A fragments in registers: row = lane&31, k = ks*16 + (lane>>5)*8 + e
    short8 ah[8], al[8];
    {
        const float* xr = X + (size_t)(rowBase + wid * 32 + col0) * DIM + hi * 8;
        #pragma unroll
        for (int ks = 0; ks < 8; ++ks) {
            float4 a = *(const float4*)(xr + ks * 16);
            float4 b = *(const float4*)(xr + ks * 16 + 4);
            float xv[8] = {a.x, a.y, a.z, a.w, b.x, b.y, b.z, b.w};
            short8 h, l;
            #pragma unroll
            for (int e = 0; e < 8; ++e) {
                unsigned short hh = f2bf(xv[e]);
                h[e] = (short)hh;
                l[e] = (short)f2bf(xv[e] - bf2f(hh));
            }
            ah[ks] = h;
            al[ks] = l;
        }
    }
    __syncthreads();

    float bd[16];
    int bi[16];
    #pragma unroll
    for (int s = 0; s < 16; ++s) { bd[s] = 1e30f; bi[s] = 0; }

    const int swz = (col0 & 15) << 4;
    const int coff = col0 * 256;
    const int khb = hi * 16;

    for (int c = 0; c < 16; ++c) {
        const int cur = c & 1;
        if (c < 15) {                    // async prefetch next chunk into buf^1
            const char* hp = ehiB + (c + 1) * 16384;
            const char* lp = eloB + (c + 1) * 16384;
            #pragma unroll
            for (int t = 0; t < 4; ++t) {
                int i = tid + t * 256;
                stage16(hp + i * 16, &es[cur ^ 1][i * 16]);
                stage16(lp + i * 16, &es[cur ^ 1][16384 + i * 16]);
            }
        }

        f32x16 acc0, acc1;
        #pragma unroll
        for (int s = 0; s < 16; ++s) { acc0[s] = 0.f; acc1[s] = 0.f; }

        const char* hb = es[cur];
        #pragma unroll
        for (int ks = 0; ks < 8; ++ks) {
            int kb = (ks * 32 + khb) ^ swz;
            short8 bh0 = *(const short8*)(hb + coff + kb);
            short8 bl0 = *(const short8*)(hb + 16384 + coff + kb);
            short8 bh1 = *(const short8*)(hb + 8192 + coff + kb);
            short8 bl1 = *(const short8*)(hb + 24576 + coff + kb);
            acc0 = __builtin_amdgcn_mfma_f32_32x32x16_bf16(ah[ks], bl0, acc0, 0, 0, 0);
            acc0 = __builtin_amdgcn_mfma_f32_32x32x16_bf16(al[ks], bh0, acc0, 0, 0, 0);
            acc0 = __builtin_amdgcn_mfma_f32_32x32x16_bf16(ah[ks], bh0, acc0, 0, 0, 0);
            acc1 = __builtin_amdgcn_mfma_f32_32x32x16_bf16(ah[ks], bl1, acc1, 0, 0, 0);
            acc1 = __builtin_amdgcn_mfma_f32_32x32x16_bf16(al[ks], bh1, acc1, 0, 0, 0);
            acc1 = __builtin_amdgcn_mfma_f32_32x32x16_bf16(ah[ks], bh1, acc1, 0, 0, 0);
        }

        // dist + running argmin. C: col=lane&31, row=(r&3)+8*(r>>2)+4*(lane>>5)
        float e0 = esq_lds[c * 64 + col0];
        float e1 = esq_lds[c * 64 + 32 + col0];
        int c0 = c * 64 + col0, c1 = c * 64 + 32 + col0;
        #pragma unroll
        for (int r = 0; r < 16; ++r) {
            float s0 = e0 - 2.f * acc0[r];
            if (s0 < bd[r]) { bd[r] = s0; bi[r] = c0; }
            float s1 = e1 - 2.f * acc1[r];
            if (s1 < bd[r]) { bd[r] = s1; bi[r] = c1; }
        }
        __syncthreads();
    }

    // ---- argmin across the 32 col-lanes (tie-break: smaller index) ----
    #pragma unroll
    for (int r = 0; r < 16; ++r) {
        #pragma unroll
        for (int off = 1; off < 32; off <<= 1) {
            float od = __shfl_xor(bd[r], off, 64);
            int oi = __shfl_xor(bi[r], off, 64);
            if (od < bd[r] || (od == bd[r] && oi < bi[r])) { bd[r] = od; bi[r] = oi; }
        }
    }
    if (col0 == 0) {
        int* cnt = (int*)(ws + WS_CNTI);
        #pragma unroll
        for (int r = 0; r < 16; ++r) {
            int row = wid * 32 + (r & 3) + 8 * (r >> 2) + 4 * hi;
            int b = bi[r];
            ind_sh[row] = b;
            out[O_IND + rowBase + row] = (float)b;
            atomicAdd(&cnt[b], 1);
        }
    }
    __syncthreads();

    // ---- quantize + ST + loss: wave writes 1KB contiguous (full lines) ----
    float lp = 0.f;
    {
        const float* et = ws + WS_ET;
        int rsub = tid >> 5;            // 8 rows per segment
        int d4 = (tid & 31) * 4;
        #pragma unroll
        for (int seg = 0; seg < 16; ++seg) {
            int row = seg * 8 + rsub;
            int j = ind_sh[row];
            float4 xv = *(const float4*)(X + (size_t)(rowBase + row) * DIM + d4);
            float4 qv = *(const float4*)(et + (size_t)j * DIM + d4);
            float4 st;
            st.x = xv.x + (qv.x - xv.x);
            st.y = xv.y + (qv.y - xv.y);
            st.z = xv.z + (qv.z - xv.z);
            st.w = xv.w + (qv.w - xv.w);
            *(float4*)(out + O_Q + (size_t)(rowBase + row) * DIM + d4) = st;
            float dx;
            dx = qv.x - xv.x; lp += dx * dx;
            dx = qv.y - xv.y; lp += dx * dx;
            dx = qv.z - xv.z; lp += dx * dx;
            dx = qv.w - xv.w; lp += dx * dx;
        }
    }
    #pragma unroll
    for (int off = 32; off; off >>= 1) lp += __shfl_down(lp, off, 64);
    if (lane == 0) red2[wid] = lp;
    __syncthreads();
    if (tid == 0) atomicAdd(ws + WS_LOSS, red2[0] + red2[1] + red2[2] + red2[3]);
}

// 1 block, 1024 threads: off=excl_scan(cnt), pos=0, n=sum(csn), CS_new, loss.
__global__ __launch_bounds__(1024) void k_scan(const float* __restrict__ CS,
                                               float* __restrict__ ws,
                                               float* __restrict__ out) {
    __shared__ int wsum[16];
    __shared__ float fsum[16];
    int tid = threadIdx.x;
    int* cnt = (int*)(ws + WS_CNTI);
    int v = cnt[tid];
    float csn = 0.99f * CS[tid] + 0.01f * (float)v;
    out[O_CS + tid] = csn;
    float s = csn;
    #pragma unroll
    for (int off = 32; off; off >>= 1) s += __shfl_down(s, off, 64);
    int sc = v;
    #pragma unroll
    for (int d = 1; d < 64; d <<= 1) {
        int t = __shfl_up(sc, d, 64);
        if ((tid & 63) >= d) sc += t;
    }
    if ((tid & 63) == 0) fsum[tid >> 6] = s;
    if ((tid & 63) == 63) wsum[tid >> 6] = sc;
    __syncthreads();
    if (tid == 0) {
        int run = 0;
        float n = 0.f;
        for (int w = 0; w < 16; ++w) {
            int t = wsum[w]; wsum[w] = run; run += t;
            n += fsum[w];
        }
        ws[WS_N] = n;
        out[O_LOSS] = ws[WS_LOSS] * (1.0f / ((float)N_ROWS * (float)DIM));
    }
    __syncthreads();
    ((int*)(ws + WS_OFF))[tid] = sc - v + wsum[tid >> 6];
    ((int*)(ws + WS_POS))[tid] = 0;
}

// one thread per row: claim slot, write row id into its code's bucket.
__global__ __launch_bounds__(256) void k_scatter(const float* __restrict__ out,
                                                 float* __restrict__ ws) {
    int i = blockIdx.x * 256 + threadIdx.x;
    int j = (int)out[O_IND + i];
    int* pos = (int*)(ws + WS_POS);
    int slot = atomicAdd(&pos[j], 1);
    ((int*)(ws + WS_BUCKET))[((int*)(ws + WS_OFF))[j] + slot] = i;
}

// block per code (128 threads = dims): 8-way-ILP gather-sum + fused EMA epilogue.
__global__ __launch_bounds__(128) void k_segsum(const float* __restrict__ X,
                                                const float* __restrict__ CS,
                                                const float* __restrict__ EA,
                                                const float* __restrict__ ws,
                                                float* __restrict__ out) {
    int j = blockIdx.x, d = threadIdx.x;
    const int* off = (const int*)(ws + WS_OFF);
    const int* cnt = (const int*)(ws + WS_CNTI);
    const int* bucket = (const int*)(ws + WS_BUCKET);
    int o = off[j], n = cnt[j];
    float a0 = 0.f, a1 = 0.f, a2 = 0.f, a3 = 0.f,
          a4 = 0.f, a5 = 0.f, a6 = 0.f, a7 = 0.f;
    int i = 0;
    for (; i + 8 <= n; i += 8) {
        a0 += X[(size_t)bucket[o + i + 0] * DIM + d];
        a1 += X[(size_t)bucket[o + i + 1] * DIM + d];
        a2 += X[(size_t)bucket[o + i + 2] * DIM + d];
        a3 += X[(size_t)bucket[o + i + 3] * DIM + d];
        a4 += X[(size_t)bucket[o + i + 4] * DIM + d];
        a5 += X[(size_t)bucket[o + i + 5] * DIM + d];
        a6 += X[(size_t)bucket[o + i + 6] * DIM + d];
        a7 += X[(size_t)bucket[o + i + 7] * DIM + d];
    }
    for (; i < n; ++i) a0 += X[(size_t)bucket[o + i] * DIM + d];
    float s = ((a0 + a1) + (a2 + a3)) + ((a4 + a5) + (a6 + a7));

    float nall = ws[WS_N];
    float csn = 0.99f * CS[j] + 0.01f * (float)n;
    float cs = (csn + 1e-5f) / (nall + (float)NE * 1e-5f) * nall;
    float ean = EA[(size_t)d * NE + j] * 0.99f + 0.01f * s;
    out[O_EAVG + (size_t)d * NE + j] = ean;
    out[O_ENEW + (size_t)d * NE + j] = ean / cs;
}

extern "C" void kernel_launch(void* const* d_in, const int* in_sizes, int n_in,
                              void* d_out, int out_size, void* d_ws, size_t ws_size,
                              hipStream_t stream) {
    const float* X = (const float*)d_in[0];    // inputs  [16,64,64,128]
    const float* E = (const float*)d_in[1];    // embed   [128,1024]
    const float* CS = (const float*)d_in[2];   // cluster_size [1024]
    const float* EA = (const float*)d_in[3];   // embed_avg    [128,1024]
    float* out = (float*)d_out;
    float* ws = (float*)d_ws;

    hipMemsetAsync(d_ws, 0, (size_t)WS_ZERO_BYTES, stream);
    k_prep   <<<dim3(16),           dim3(256),  0, stream>>>(E, ws);
    k_main   <<<dim3(N_ROWS / 128), dim3(256),  0, stream>>>(X, ws, out);
    k_scan   <<<dim3(1),            dim3(1024), 0, stream>>>(CS, ws, out);
    k_scatter<<<dim3(N_ROWS / 256), dim3(256),  0, stream>>>(out, ws);
    k_segsum <<<dim3(NE),           dim3(128),  0, stream>>>(X, CS, EA, ws, out);
}

// Round 5
// 215.081 us; speedup vs baseline: 3.8630x; 1.3826x over previous
//
#include <hip/hip_runtime.h>

// VectorQuantizerEMA forward on MI355X (gfx950).
// memset(528KB: esq/cnt/loss/esum) -> k_prep (bf16 hi/lo split of E into
// swizzled 32x32x16-MFMA B-images + E^T + ||e||^2) -> k_main (32x32x16
// bf16-split MFMA argmin + coalesced quantize/ST/loss; 1 int atomic/row)
// -> k_scan (prefix-sum, n, cluster_size_new, loss) -> k_scatter (row->bucket)
// -> k_segsum (position-parallel ordered segment-sum, ~2K atomic flushes)
// -> k_final (EMA update / normalize, coalesced).

#define N_ROWS 65536
#define DIM 128
#define NE 1024

typedef __attribute__((ext_vector_type(8))) short short8;
typedef __attribute__((ext_vector_type(16))) float f32x16;

// ws float offsets
#define WS_ESQ    0
#define WS_CNTI   1024                  // 1024 ints
#define WS_LOSS   2048
#define WS_N      2049
#define WS_ESUM   4096                  // [128 dims][1024 codes] fp32, atomic target
#define WS_EHI    (WS_ESUM + DIM*NE)    // 256KB bf16-hi image (16 chunks x 16KB)
#define WS_ELO    (WS_EHI + 65536)      // 256KB bf16-lo image
#define WS_ET     (WS_ELO + 65536)      // [1024][128] fp32 transposed embed
#define WS_BUCKET (WS_ET + DIM*NE)      // 65536 ints: row ids grouped by code
#define WS_OFF    (WS_BUCKET + N_ROWS)  // 1024 ints
#define WS_POS    (WS_OFF + 1024)       // 1024 ints
#define WS_ZERO_BYTES ((WS_ESUM + DIM*NE) * 4)

// out float offsets (reference return order)
#define O_Q    0
#define O_IND  (N_ROWS*DIM)
#define O_LOSS (O_IND + N_ROWS)
#define O_ENEW (O_LOSS + 1)
#define O_CS   (O_ENEW + DIM*NE)
#define O_EAVG (O_CS + NE)

__device__ __forceinline__ unsigned short f2bf(float f) {
    unsigned u = __float_as_uint(f);
    unsigned r = (u + 0x7fffu + ((u >> 16) & 1u)) >> 16;
    return (unsigned short)r;
}
__device__ __forceinline__ float bf2f(unsigned short h) {
    return __uint_as_float(((unsigned)h) << 16);
}
__device__ __forceinline__ void stage16(const void* g, void* l) {
    __builtin_amdgcn_global_load_lds(
        (const __attribute__((address_space(1))) unsigned*)g,
        (__attribute__((address_space(3))) unsigned*)l, 16, 0, 0);
}

// Image layout (per 64-code chunk, 16KB): byte = c*256 + ((k*2) ^ ((c&15)<<4)).
__global__ __launch_bounds__(256) void k_prep(const float* __restrict__ E,
                                              float* __restrict__ ws) {
    __shared__ float ls[64 * 129];      // [c][k], pad 129 vs bank conflicts
    __shared__ float part[4][64];
    const int tid = threadIdx.x, b = blockIdx.x;
    const int lane = tid & 63, wid = tid >> 6;

    float sq = 0.f;
    #pragma unroll
    for (int t = 0; t < 32; ++t) {      // k = 4t + wid, c = lane (coalesced 256B)
        int k = t * 4 + wid;
        float v = E[k * NE + b * 64 + lane];
        ls[lane * 129 + k] = v;
        sq += v * v;
    }
    part[wid][lane] = sq;
    __syncthreads();
    if (tid < 64)
        ws[WS_ESQ + b * 64 + tid] =
            part[0][tid] + part[1][tid] + part[2][tid] + part[3][tid];

    char* ehiB = (char*)(ws + WS_EHI);
    char* eloB = (char*)(ws + WS_ELO);
    #pragma unroll
    for (int t = 0; t < 4; ++t) {       // 1024 16B-blocks per image
        int i = tid + t * 256;
        int c = i >> 4, slot = i & 15;
        int k0 = (slot ^ (c & 15)) * 8;
        short8 hv, lv;
        #pragma unroll
        for (int e = 0; e < 8; ++e) {
            float v = ls[c * 129 + k0 + e];
            unsigned short h = f2bf(v);
            hv[e] = (short)h;
            lv[e] = (short)f2bf(v - bf2f(h));
        }
        *(short8*)(ehiB + (size_t)b * 16384 + i * 16) = hv;
        *(short8*)(eloB + (size_t)b * 16384 + i * 16) = lv;
    }
    float* et = ws + WS_ET;
    #pragma unroll
    for (int t = 0; t < 8; ++t) {       // 2048 float4 per chunk
        int i = tid + t * 256;
        int c = i >> 5, k4 = (i & 31) * 4;
        float4 v;
        v.x = ls[c * 129 + k4 + 0];
        v.y = ls[c * 129 + k4 + 1];
        v.z = ls[c * 129 + k4 + 2];
        v.w = ls[c * 129 + k4 + 3];
        *(float4*)(et + (size_t)(b * 64 + c) * DIM + k4) = v;
    }
}

// 256 threads = 4 waves; 128 rows/block (wave: 32 rows); 16 chunks of 64 codes.
// dist_j = ||e_j||^2 - 2*x.e_j via 3-pass bf16-split 32x32x16 MFMA.
__global__ __launch_bounds__(256, 2) void k_main(const float* __restrict__ X,
                                                 float* __restrict__ ws,
                                                 float* __restrict__ out) {
    __shared__ __align__(16) char es[2][32768];   // [buf][ hi 16KB | lo 16KB ]
    __shared__ __align__(16) float esq_lds[NE];
    __shared__ int ind_sh[128];
    __shared__ float red2[4];

    const int tid = threadIdx.x;
    const int lane = tid & 63;
    const int wid = tid >> 6;
    const int col0 = lane & 31;
    const int hi = lane >> 5;
    const int rowBase = blockIdx.x * 128;

    const char* ehiB = (const char*)(ws + WS_EHI);
    const char* eloB = (const char*)(ws + WS_ELO);

    // stage chunk 0 (async DMA) before A-frag work
    #pragma unroll
    for (int t = 0; t < 4; ++t) {
        int i = tid + t * 256;
        stage16(ehiB + i * 16, &es[0][i * 16]);
        stage16(eloB + i * 16, &es[0][16384 + i * 16]);
    }

    ((float4*)esq_lds)[tid] = ((const float4*)(ws + WS_ESQ))[tid];

    // ---- A fragments in registers: row = lane&31, k = ks*16 + (lane>>5)*8 + e
    short8 ah[8], al[8];
    {
        const float* xr = X + (size_t)(rowBase + wid * 32 + col0) * DIM + hi * 8;
        #pragma unroll
        for (int ks = 0; ks < 8; ++ks) {
            float4 a = *(const float4*)(xr + ks * 16);
            float4 b = *(const float4*)(xr + ks * 16 + 4);
            float xv[8] = {a.x, a.y, a.z, a.w, b.x, b.y, b.z, b.w};
            short8 h, l;
            #pragma unroll
            for (int e = 0; e < 8; ++e) {
                unsigned short hh = f2bf(xv[e]);
                h[e] = (short)hh;
                l[e] = (short)f2bf(xv[e] - bf2f(hh));
            }
            ah[ks] = h;
            al[ks] = l;
        }
    }
    __syncthreads();

    float bd[16];
    int bi[16];
    #pragma unroll
    for (int s = 0; s < 16; ++s) { bd[s] = 1e30f; bi[s] = 0; }

    const int swz = (col0 & 15) << 4;
    const int coff = col0 * 256;
    const int khb = hi * 16;

    for (int c = 0; c < 16; ++c) {
        const int cur = c & 1;
        if (c < 15) {                    // async prefetch next chunk into buf^1
            const char* hp = ehiB + (c + 1) * 16384;
            const char* lp = eloB + (c + 1) * 16384;
            #pragma unroll
            for (int t = 0; t < 4; ++t) {
                int i = tid + t * 256;
                stage16(hp + i * 16, &es[cur ^ 1][i * 16]);
                stage16(lp + i * 16, &es[cur ^ 1][16384 + i * 16]);
            }
        }

        f32x16 acc0, acc1;
        #pragma unroll
        for (int s = 0; s < 16; ++s) { acc0[s] = 0.f; acc1[s] = 0.f; }

        const char* hb = es[cur];
        #pragma unroll
        for (int ks = 0; ks < 8; ++ks) {
            int kb = (ks * 32 + khb) ^ swz;
            short8 bh0 = *(const short8*)(hb + coff + kb);
            short8 bl0 = *(const short8*)(hb + 16384 + coff + kb);
            short8 bh1 = *(const short8*)(hb + 8192 + coff + kb);
            short8 bl1 = *(const short8*)(hb + 24576 + coff + kb);
            acc0 = __builtin_amdgcn_mfma_f32_32x32x16_bf16(ah[ks], bl0, acc0, 0, 0, 0);
            acc0 = __builtin_amdgcn_mfma_f32_32x32x16_bf16(al[ks], bh0, acc0, 0, 0, 0);
            acc0 = __builtin_amdgcn_mfma_f32_32x32x16_bf16(ah[ks], bh0, acc0, 0, 0, 0);
            acc1 = __builtin_amdgcn_mfma_f32_32x32x16_bf16(ah[ks], bl1, acc1, 0, 0, 0);
            acc1 = __builtin_amdgcn_mfma_f32_32x32x16_bf16(al[ks], bh1, acc1, 0, 0, 0);
            acc1 = __builtin_amdgcn_mfma_f32_32x32x16_bf16(ah[ks], bh1, acc1, 0, 0, 0);
        }

        // dist + running argmin. C: col=lane&31, row=(r&3)+8*(r>>2)+4*(lane>>5)
        float e0 = esq_lds[c * 64 + col0];
        float e1 = esq_lds[c * 64 + 32 + col0];
        int c0 = c * 64 + col0, c1 = c * 64 + 32 + col0;
        #pragma unroll
        for (int r = 0; r < 16; ++r) {
            float s0 = e0 - 2.f * acc0[r];
            if (s0 < bd[r]) { bd[r] = s0; bi[r] = c0; }
            float s1 = e1 - 2.f * acc1[r];
            if (s1 < bd[r]) { bd[r] = s1; bi[r] = c1; }
        }
        __syncthreads();
    }

    // ---- argmin across the 32 col-lanes (tie-break: smaller index) ----
    #pragma unroll
    for (int r = 0; r < 16; ++r) {
        #pragma unroll
        for (int off = 1; off < 32; off <<= 1) {
            float od = __shfl_xor(bd[r], off, 64);
            int oi = __shfl_xor(bi[r], off, 64);
            if (od < bd[r] || (od == bd[r] && oi < bi[r])) { bd[r] = od; bi[r] = oi; }
        }
    }
    if (col0 == 0) {
        int* cnt = (int*)(ws + WS_CNTI);
        #pragma unroll
        for (int r = 0; r < 16; ++r) {
            int row = wid * 32 + (r & 3) + 8 * (r >> 2) + 4 * hi;
            int b = bi[r];
            ind_sh[row] = b;
            out[O_IND + rowBase + row] = (float)b;
            atomicAdd(&cnt[b], 1);
        }
    }
    __syncthreads();

    // ---- quantize + ST + loss: wave writes 1KB contiguous (full lines) ----
    float lp = 0.f;
    {
        const float* et = ws + WS_ET;
        int rsub = tid >> 5;            // 8 rows per segment
        int d4 = (tid & 31) * 4;
        #pragma unroll
        for (int seg = 0; seg < 16; ++seg) {
            int row = seg * 8 + rsub;
            int j = ind_sh[row];
            float4 xv = *(const float4*)(X + (size_t)(rowBase + row) * DIM + d4);
            float4 qv = *(const float4*)(et + (size_t)j * DIM + d4);
            float4 st;
            st.x = xv.x + (qv.x - xv.x);
            st.y = xv.y + (qv.y - xv.y);
            st.z = xv.z + (qv.z - xv.z);
            st.w = xv.w + (qv.w - xv.w);
            *(float4*)(out + O_Q + (size_t)(rowBase + row) * DIM + d4) = st;
            float dx;
            dx = qv.x - xv.x; lp += dx * dx;
            dx = qv.y - xv.y; lp += dx * dx;
            dx = qv.z - xv.z; lp += dx * dx;
            dx = qv.w - xv.w; lp += dx * dx;
        }
    }
    #pragma unroll
    for (int off = 32; off; off >>= 1) lp += __shfl_down(lp, off, 64);
    if (lane == 0) red2[wid] = lp;
    __syncthreads();
    if (tid == 0) atomicAdd(ws + WS_LOSS, red2[0] + red2[1] + red2[2] + red2[3]);
}

// 1 block, 1024 threads: off=excl_scan(cnt), pos=0, n=sum(csn), CS_new, loss.
__global__ __launch_bounds__(1024) void k_scan(const float* __restrict__ CS,
                                               float* __restrict__ ws,
                                               float* __restrict__ out) {
    __shared__ int wsum[16];
    __shared__ float fsum[16];
    int tid = threadIdx.x;
    int* cnt = (int*)(ws + WS_CNTI);
    int v = cnt[tid];
    float csn = 0.99f * CS[tid] + 0.01f * (float)v;
    out[O_CS + tid] = csn;
    float s = csn;
    #pragma unroll
    for (int off = 32; off; off >>= 1) s += __shfl_down(s, off, 64);
    int sc = v;
    #pragma unroll
    for (int d = 1; d < 64; d <<= 1) {
        int t = __shfl_up(sc, d, 64);
        if ((tid & 63) >= d) sc += t;
    }
    if ((tid & 63) == 0) fsum[tid >> 6] = s;
    if ((tid & 63) == 63) wsum[tid >> 6] = sc;
    __syncthreads();
    if (tid == 0) {
        int run = 0;
        float n = 0.f;
        for (int w = 0; w < 16; ++w) {
            int t = wsum[w]; wsum[w] = run; run += t;
            n += fsum[w];
        }
        ws[WS_N] = n;
        out[O_LOSS] = ws[WS_LOSS] * (1.0f / ((float)N_ROWS * (float)DIM));
    }
    __syncthreads();
    ((int*)(ws + WS_OFF))[tid] = sc - v + wsum[tid >> 6];
    ((int*)(ws + WS_POS))[tid] = 0;
}

// one thread per row: claim slot, write row id into its code's bucket.
__global__ __launch_bounds__(256) void k_scatter(const float* __restrict__ out,
                                                 float* __restrict__ ws) {
    int i = blockIdx.x * 256 + threadIdx.x;
    int j = (int)out[O_IND + i];
    int* pos = (int*)(ws + WS_POS);
    int slot = atomicAdd(&pos[j], 1);
    ((int*)(ws + WS_BUCKET))[((int*)(ws + WS_OFF))[j] + slot] = i;
}

// Position-parallel ordered segment-sum: block b owns bucket positions
// [b*64, b*64+64); thread = dim d. Walk sorted positions, flush one atomic
// per (dim, code-run). Load-balanced regardless of cluster-size skew.
__global__ __launch_bounds__(128) void k_segsum(const float* __restrict__ X,
                                                float* __restrict__ ws) {
    __shared__ int offL[1025];
    __shared__ int rs[64];
    const int tid = threadIdx.x;
    const int p0 = blockIdx.x * 64;
    const int* off = (const int*)(ws + WS_OFF);
    #pragma unroll
    for (int t = 0; t < 8; ++t) offL[tid + t * 128] = off[tid + t * 128];
    if (tid == 0) offL[1024] = N_ROWS;
    if (tid < 64) rs[tid] = ((const int*)(ws + WS_BUCKET))[p0 + tid];
    __syncthreads();

    // largest j with offL[j] <= p0
    int lo = 0, hi2 = 1023;
    while (lo < hi2) {
        int mid = (lo + hi2 + 1) >> 1;
        if (offL[mid] <= p0) lo = mid; else hi2 = mid - 1;
    }
    int j = lo;
    int bnd = offL[j + 1];
    float* esum = ws + WS_ESUM;
    float acc = 0.f;
    #pragma unroll 2
    for (int base = 0; base < 64; base += 8) {
        float v[8];
        #pragma unroll
        for (int u = 0; u < 8; ++u)
            v[u] = X[(size_t)rs[base + u] * DIM + tid];
        #pragma unroll
        for (int u = 0; u < 8; ++u) {
            int p = p0 + base + u;
            if (p >= bnd) {
                atomicAdd(&esum[tid * NE + j], acc);
                acc = 0.f;
                do { ++j; bnd = offL[j + 1]; } while (p >= bnd);
            }
            acc += v[u];
        }
    }
    atomicAdd(&esum[tid * NE + j], acc);
}

// EMA update / normalize; fully coalesced over codes j.
__global__ __launch_bounds__(256) void k_final(const float* __restrict__ CS,
                                               const float* __restrict__ EA,
                                               const float* __restrict__ ws,
                                               float* __restrict__ out) {
    int d = blockIdx.x >> 2;
    int j = (blockIdx.x & 3) * 256 + threadIdx.x;
    float nall = ws[WS_N];
    float csn = 0.99f * CS[j] + 0.01f * (float)((const int*)(ws + WS_CNTI))[j];
    float cs = (csn + 1e-5f) / (nall + (float)NE * 1e-5f) * nall;
    float ean = EA[(size_t)d * NE + j] * 0.99f + 0.01f * ws[WS_ESUM + (size_t)d * NE + j];
    out[O_EAVG + (size_t)d * NE + j] = ean;
    out[O_ENEW + (size_t)d * NE + j] = ean / cs;
}

extern "C" void kernel_launch(void* const* d_in, const int* in_sizes, int n_in,
                              void* d_out, int out_size, void* d_ws, size_t ws_size,
                              hipStream_t stream) {
    const float* X = (const float*)d_in[0];    // inputs  [16,64,64,128]
    const float* E = (const float*)d_in[1];    // embed   [128,1024]
    const float* CS = (const float*)d_in[2];   // cluster_size [1024]
    const float* EA = (const float*)d_in[3];   // embed_avg    [128,1024]
    float* out = (float*)d_out;
    float* ws = (float*)d_ws;

    hipMemsetAsync(d_ws, 0, (size_t)WS_ZERO_BYTES, stream);
    k_prep   <<<dim3(16),           dim3(256),  0, stream>>>(E, ws);
    k_main   <<<dim3(N_ROWS / 128), dim3(256),  0, stream>>>(X, ws, out);
    k_scan   <<<dim3(1),            dim3(1024), 0, stream>>>(CS, ws, out);
    k_scatter<<<dim3(N_ROWS / 256), dim3(256),  0, stream>>>(out, ws);
    k_segsum <<<dim3(N_ROWS / 64),  dim3(128),  0, stream>>>(X, ws);
    k_final  <<<dim3(512),          dim3(256),  0, stream>>>(CS, EA, ws, out);
}

// Round 6
// 204.165 us; speedup vs baseline: 4.0696x; 1.0535x over previous
//
#include <hip/hip_runtime.h>

// VectorQuantizerEMA forward on MI355X (gfx950).
// memset(540KB: esq/cnt/loss/esum) -> k_prep (64 blocks: bf16-hi image of E
// (swizzled for 32x32x16 MFMA B-frags) + E^T + partial ||e||^2)
// -> k_main (2-pass bf16-split MFMA argmin: x.e=(xh+xl).eh; 4 indep acc chains;
//    coalesced quantize/ST/loss; 1 int atomic/row) -> k_scan -> k_scatter
// -> k_segsum (position-parallel ordered segment-sum) -> k_final (EMA).

#define N_ROWS 65536
#define DIM 128
#define NE 1024

typedef __attribute__((ext_vector_type(8))) short short8;
typedef __attribute__((ext_vector_type(16))) float f32x16;

// ws float offsets
#define WS_ESQ    0
#define WS_CNTI   1024                  // 1024 ints
#define WS_LOSS   2048
#define WS_N      2049
#define WS_ESUM   4096                  // [128 dims][1024 codes] fp32, atomic target
#define WS_EHI    (WS_ESUM + DIM*NE)    // 256KB bf16-hi image (16 chunks x 16KB)
#define WS_ET     (WS_EHI + 65536)      // [1024][128] fp32 transposed embed
#define WS_BUCKET (WS_ET + DIM*NE)      // 65536 ints: row ids grouped by code
#define WS_OFF    (WS_BUCKET + N_ROWS)  // 1024 ints
#define WS_POS    (WS_OFF + 1024)       // 1024 ints
#define WS_ZERO_BYTES ((WS_ESUM + DIM*NE) * 4)

// out float offsets (reference return order)
#define O_Q    0
#define O_IND  (N_ROWS*DIM)
#define O_LOSS (O_IND + N_ROWS)
#define O_ENEW (O_LOSS + 1)
#define O_CS   (O_ENEW + DIM*NE)
#define O_EAVG (O_CS + NE)

__device__ __forceinline__ unsigned short f2bf(float f) {
    unsigned u = __float_as_uint(f);
    unsigned r = (u + 0x7fffu + ((u >> 16) & 1u)) >> 16;
    return (unsigned short)r;
}
__device__ __forceinline__ float bf2f(unsigned short h) {
    return __uint_as_float(((unsigned)h) << 16);
}
__device__ __forceinline__ void stage16(const void* g, void* l) {
    __builtin_amdgcn_global_load_lds(
        (const __attribute__((address_space(1))) unsigned*)g,
        (__attribute__((address_space(3))) unsigned*)l, 16, 0, 0);
}

// Image layout (per 64-code chunk, 16KB): byte = c*256 + ((k*2) ^ ((c&15)<<4)),
// i.e. 16B slot s of code-row c holds k = (s^(c&15))*8 .. +7.
// Grid 64: block = (chunk b = bx>>2, k-quarter kq = bx&3).
__global__ __launch_bounds__(256) void k_prep(const float* __restrict__ E,
                                              float* __restrict__ ws) {
    __shared__ float ls[64][33];        // [c][k-local], padded
    __shared__ float part[4][64];
    const int tid = threadIdx.x;
    const int b = blockIdx.x >> 2, kq = blockIdx.x & 3;
    const int lane = tid & 63, wid = tid >> 6;

    float sq = 0.f;
    #pragma unroll
    for (int t = 0; t < 8; ++t) {       // k-local = 4t+wid, c = lane (coalesced)
        int kk = t * 4 + wid;
        float v = E[(kq * 32 + kk) * NE + b * 64 + lane];
        ls[lane][kk] = v;
        sq += v * v;
    }
    part[wid][lane] = sq;
    __syncthreads();
    if (tid < 64)
        atomicAdd(ws + WS_ESQ + b * 64 + tid,
                  part[0][tid] + part[1][tid] + part[2][tid] + part[3][tid]);

    {   // hi image: 256 16B-slots for this (chunk, k-quarter)
        int c = tid >> 2, u = tid & 3;
        int kk8 = kq * 4 + u;           // global k/8
        int slot = kk8 ^ (c & 15);
        short8 hv;
        #pragma unroll
        for (int e = 0; e < 8; ++e)
            hv[e] = (short)f2bf(ls[c][u * 8 + e]);
        *(short8*)((char*)(ws + WS_EHI) + (size_t)b * 16384 + c * 256 + slot * 16) = hv;
    }
    float* et = ws + WS_ET;
    #pragma unroll
    for (int t = 0; t < 2; ++t) {       // E^T: 512 float4 per block
        int i = tid + t * 256;
        int c = i >> 3, k4i = i & 7;
        float4 v;
        v.x = ls[c][k4i * 4 + 0];
        v.y = ls[c][k4i * 4 + 1];
        v.z = ls[c][k4i * 4 + 2];
        v.w = ls[c][k4i * 4 + 3];
        *(float4*)(et + (size_t)(b * 64 + c) * DIM + kq * 32 + k4i * 4) = v;
    }
}

// 256 threads = 4 waves; 128 rows/block (wave: 32 rows); 16 chunks of 64 codes.
// dist_j = ||e_j||^2 - 2*(xh.eh + xl.eh); 4 independent MFMA chains per chunk.
__global__ __launch_bounds__(256, 2) void k_main(const float* __restrict__ X,
                                                 float* __restrict__ ws,
                                                 float* __restrict__ out) {
    __shared__ __align__(16) char es[2][16384];   // hi-image chunk double-buffer
    __shared__ __align__(16) float esq_lds[NE];
    __shared__ int ind_sh[128];
    __shared__ float red2[4];

    const int tid = threadIdx.x;
    const int lane = tid & 63;
    const int wid = tid >> 6;
    const int col0 = lane & 31;
    const int hi = lane >> 5;
    const int rowBase = blockIdx.x * 128;

    const char* ehiB = (const char*)(ws + WS_EHI);

    // stage chunk 0 (async DMA) before A-frag work
    #pragma unroll
    for (int t = 0; t < 4; ++t) {
        int i = tid + t * 256;
        stage16(ehiB + i * 16, &es[0][i * 16]);
    }

    ((float4*)esq_lds)[tid] = ((const float4*)(ws + WS_ESQ))[tid];

    // ---- A fragments in registers: row = lane&31, k = ks*16 + (lane>>5)*8 + e
    short8 ah[8], al[8];
    {
        const float* xr = X + (size_t)(rowBase + wid * 32 + col0) * DIM + hi * 8;
        #pragma unroll
        for (int ks = 0; ks < 8; ++ks) {
            float4 a = *(const float4*)(xr + ks * 16);
            float4 b = *(const float4*)(xr + ks * 16 + 4);
            float xv[8] = {a.x, a.y, a.z, a.w, b.x, b.y, b.z, b.w};
            short8 h, l;
            #pragma unroll
            for (int e = 0; e < 8; ++e) {
                unsigned short hh = f2bf(xv[e]);
                h[e] = (short)hh;
                l[e] = (short)f2bf(xv[e] - bf2f(hh));
            }
            ah[ks] = h;
            al[ks] = l;
        }
    }
    __syncthreads();

    float bd[16];
    int bi[16];
    #pragma unroll
    for (int s = 0; s < 16; ++s) { bd[s] = 1e30f; bi[s] = 0; }

    const int swz = (col0 & 15) << 4;
    const int coff = col0 * 256;
    const int khb = hi * 16;

    for (int c = 0; c < 16; ++c) {
        const int cur = c & 1;
        if (c < 15) {                    // async prefetch next chunk into buf^1
            const char* hp = ehiB + (c + 1) * 16384;
            #pragma unroll
            for (int t = 0; t < 4; ++t) {
                int i = tid + t * 256;
                stage16(hp + i * 16, &es[cur ^ 1][i * 16]);
            }
        }

        f32x16 h0, l0, h1, l1;           // 4 independent accumulate chains
        #pragma unroll
        for (int s = 0; s < 16; ++s) { h0[s] = 0.f; l0[s] = 0.f; h1[s] = 0.f; l1[s] = 0.f; }

        const char* hb = es[cur];
        #pragma unroll
        for (int ks = 0; ks < 8; ++ks) {
            int kb = (ks * 32 + khb) ^ swz;
            short8 bh0 = *(const short8*)(hb + coff + kb);
            short8 bh1 = *(const short8*)(hb + 8192 + coff + kb);
            h0 = __builtin_amdgcn_mfma_f32_32x32x16_bf16(ah[ks], bh0, h0, 0, 0, 0);
            l0 = __builtin_amdgcn_mfma_f32_32x32x16_bf16(al[ks], bh0, l0, 0, 0, 0);
            h1 = __builtin_amdgcn_mfma_f32_32x32x16_bf16(ah[ks], bh1, h1, 0, 0, 0);
            l1 = __builtin_amdgcn_mfma_f32_32x32x16_bf16(al[ks], bh1, l1, 0, 0, 0);
        }

        // dist + running argmin. C: col=lane&31, row=(r&3)+8*(r>>2)+4*(lane>>5)
        float e0 = esq_lds[c * 64 + col0];
        float e1 = esq_lds[c * 64 + 32 + col0];
        int c0 = c * 64 + col0, c1 = c * 64 + 32 + col0;
        #pragma unroll
        for (int r = 0; r < 16; ++r) {
            float s0 = e0 - 2.f * (h0[r] + l0[r]);
            if (s0 < bd[r]) { bd[r] = s0; bi[r] = c0; }
            float s1 = e1 - 2.f * (h1[r] + l1[r]);
            if (s1 < bd[r]) { bd[r] = s1; bi[r] = c1; }
        }
        __syncthreads();
    }

    // ---- argmin across the 32 col-lanes (tie-break: smaller index) ----
    #pragma unroll
    for (int r = 0; r < 16; ++r) {
        #pragma unroll
        for (int off = 1; off < 32; off <<= 1) {
            float od = __shfl_xor(bd[r], off, 64);
            int oi = __shfl_xor(bi[r], off, 64);
            if (od < bd[r] || (od == bd[r] && oi < bi[r])) { bd[r] = od; bi[r] = oi; }
        }
    }
    if (col0 == 0) {
        int* cnt = (int*)(ws + WS_CNTI);
        #pragma unroll
        for (int r = 0; r < 16; ++r) {
            int row = wid * 32 + (r & 3) + 8 * (r >> 2) + 4 * hi;
            int b = bi[r];
            ind_sh[row] = b;
            out[O_IND + rowBase + row] = (float)b;
            atomicAdd(&cnt[b], 1);
        }
    }
    __syncthreads();

    // ---- quantize + ST + loss: wave writes 1KB contiguous (full lines) ----
    float lp = 0.f;
    {
        const float* et = ws + WS_ET;
        int rsub = tid >> 5;            // 8 rows per segment
        int d4 = (tid & 31) * 4;
        #pragma unroll
        for (int seg = 0; seg < 16; ++seg) {
            int row = seg * 8 + rsub;
            int j = ind_sh[row];
            float4 xv = *(const float4*)(X + (size_t)(rowBase + row) * DIM + d4);
            float4 qv = *(const float4*)(et + (size_t)j * DIM + d4);
            float4 st;
            st.x = xv.x + (qv.x - xv.x);
            st.y = xv.y + (qv.y - xv.y);
            st.z = xv.z + (qv.z - xv.z);
            st.w = xv.w + (qv.w - xv.w);
            *(float4*)(out + O_Q + (size_t)(rowBase + row) * DIM + d4) = st;
            float dx;
            dx = qv.x - xv.x; lp += dx * dx;
            dx = qv.y - xv.y; lp += dx * dx;
            dx = qv.z - xv.z; lp += dx * dx;
            dx = qv.w - xv.w; lp += dx * dx;
        }
    }
    #pragma unroll
    for (int off = 32; off; off >>= 1) lp += __shfl_down(lp, off, 64);
    if (lane == 0) red2[wid] = lp;
    __syncthreads();
    if (tid == 0) atomicAdd(ws + WS_LOSS, red2[0] + red2[1] + red2[2] + red2[3]);
}

// 1 block, 1024 threads: off=excl_scan(cnt), pos=0, n=sum(csn), CS_new, loss.
__global__ __launch_bounds__(1024) void k_scan(const float* __restrict__ CS,
                                               float* __restrict__ ws,
                                               float* __restrict__ out) {
    __shared__ int wsum[16];
    __shared__ float fsum[16];
    int tid = threadIdx.x;
    int* cnt = (int*)(ws + WS_CNTI);
    int v = cnt[tid];
    float csn = 0.99f * CS[tid] + 0.01f * (float)v;
    out[O_CS + tid] = csn;
    float s = csn;
    #pragma unroll
    for (int off = 32; off; off >>= 1) s += __shfl_down(s, off, 64);
    int sc = v;
    #pragma unroll
    for (int d = 1; d < 64; d <<= 1) {
        int t = __shfl_up(sc, d, 64);
        if ((tid & 63) >= d) sc += t;
    }
    if ((tid & 63) == 0) fsum[tid >> 6] = s;
    if ((tid & 63) == 63) wsum[tid >> 6] = sc;
    __syncthreads();
    if (tid == 0) {
        int run = 0;
        float n = 0.f;
        for (int w = 0; w < 16; ++w) {
            int t = wsum[w]; wsum[w] = run; run += t;
            n += fsum[w];
        }
        ws[WS_N] = n;
        out[O_LOSS] = ws[WS_LOSS] * (1.0f / ((float)N_ROWS * (float)DIM));
    }
    __syncthreads();
    ((int*)(ws + WS_OFF))[tid] = sc - v + wsum[tid >> 6];
    ((int*)(ws + WS_POS))[tid] = 0;
}

// one thread per row: claim slot, write row id into its code's bucket.
__global__ __launch_bounds__(256) void k_scatter(const float* __restrict__ out,
                                                 float* __restrict__ ws) {
    int i = blockIdx.x * 256 + threadIdx.x;
    int j = (int)out[O_IND + i];
    int* pos = (int*)(ws + WS_POS);
    int slot = atomicAdd(&pos[j], 1);
    ((int*)(ws + WS_BUCKET))[((int*)(ws + WS_OFF))[j] + slot] = i;
}

// Position-parallel ordered segment-sum: block b owns bucket positions
// [b*64, b*64+64); thread = dim d. One atomic flush per (dim, code-run).
__global__ __launch_bounds__(128) void k_segsum(const float* __restrict__ X,
                                                float* __restrict__ ws) {
    __shared__ int offL[1025];
    __shared__ int rs[64];
    const int tid = threadIdx.x;
    const int p0 = blockIdx.x * 64;
    const int* off = (const int*)(ws + WS_OFF);
    #pragma unroll
    for (int t = 0; t < 8; ++t) offL[tid + t * 128] = off[tid + t * 128];
    if (tid == 0) offL[1024] = N_ROWS;
    if (tid < 64) rs[tid] = ((const int*)(ws + WS_BUCKET))[p0 + tid];
    __syncthreads();

    int lo = 0, hi2 = 1023;             // largest j with offL[j] <= p0
    while (lo < hi2) {
        int mid = (lo + hi2 + 1) >> 1;
        if (offL[mid] <= p0) lo = mid; else hi2 = mid - 1;
    }
    int j = lo;
    int bnd = offL[j + 1];
    float* esum = ws + WS_ESUM;
    float acc = 0.f;
    #pragma unroll 2
    for (int base = 0; base < 64; base += 8) {
        float v[8];
        #pragma unroll
        for (int u = 0; u < 8; ++u)
            v[u] = X[(size_t)rs[base + u] * DIM + tid];
        #pragma unroll
        for (int u = 0; u < 8; ++u) {
            int p = p0 + base + u;
            if (p >= bnd) {
                atomicAdd(&esum[tid * NE + j], acc);
                acc = 0.f;
                do { ++j; bnd = offL[j + 1]; } while (p >= bnd);
            }
            acc += v[u];
        }
    }
    atomicAdd(&esum[tid * NE + j], acc);
}

// EMA update / normalize; fully coalesced over codes j.
__global__ __launch_bounds__(256) void k_final(const float* __restrict__ CS,
                                               const float* __restrict__ EA,
                                               const float* __restrict__ ws,
                                               float* __restrict__ out) {
    int d = blockIdx.x >> 2;
    int j = (blockIdx.x & 3) * 256 + threadIdx.x;
    float nall = ws[WS_N];
    float csn = 0.99f * CS[j] + 0.01f * (float)((const int*)(ws + WS_CNTI))[j];
    float cs = (csn + 1e-5f) / (nall + (float)NE * 1e-5f) * nall;
    float ean = EA[(size_t)d * NE + j] * 0.99f + 0.01f * ws[WS_ESUM + (size_t)d * NE + j];
    out[O_EAVG + (size_t)d * NE + j] = ean;
    out[O_ENEW + (size_t)d * NE + j] = ean / cs;
}

extern "C" void kernel_launch(void* const* d_in, const int* in_sizes, int n_in,
                              void* d_out, int out_size, void* d_ws, size_t ws_size,
                              hipStream_t stream) {
    const float* X = (const float*)d_in[0];    // inputs  [16,64,64,128]
    const float* E = (const float*)d_in[1];    // embed   [128,1024]
    const float* CS = (const float*)d_in[2];   // cluster_size [1024]
    const float* EA = (const float*)d_in[3];   // embed_avg    [128,1024]
    float* out = (float*)d_out;
    float* ws = (float*)d_ws;

    hipMemsetAsync(d_ws, 0, (size_t)WS_ZERO_BYTES, stream);
    k_prep   <<<dim3(64),           dim3(256),  0, stream>>>(E, ws);
    k_main   <<<dim3(N_ROWS / 128), dim3(256),  0, stream>>>(X, ws, out);
    k_scan   <<<dim3(1),            dim3(1024), 0, stream>>>(CS, ws, out);
    k_scatter<<<dim3(N_ROWS / 256), dim3(256),  0, stream>>>(out, ws);
    k_segsum <<<dim3(N_ROWS / 64),  dim3(128),  0, stream>>>(X, ws);
    k_final  <<<dim3(512),          dim3(256),  0, stream>>>(CS, EA, ws, out);
}

// Round 7
// 195.581 us; speedup vs baseline: 4.2482x; 1.0439x over previous
//
#include <hip/hip_runtime.h>

// VectorQuantizerEMA forward on MI355X (gfx950).
// memset(540KB) -> k_prep (bf16 image of E (swizzled 32x32x16 B-frags) + E^T +
// partial ||e||^2) -> k_main (single-pass bf16 MFMA argmin, 8 waves/block
// code-split for 4 waves/SIMD occupancy; coalesced quantize/ST/loss)
// -> k_scan -> k_scatter -> k_segsum (position-parallel ordered segment-sum)
// -> k_final (EMA update / normalize).

#define N_ROWS 65536
#define DIM 128
#define NE 1024

typedef __attribute__((ext_vector_type(8))) short short8;
typedef __attribute__((ext_vector_type(16))) float f32x16;

// ws float offsets
#define WS_ESQ    0
#define WS_CNTI   1024                  // 1024 ints
#define WS_LOSS   2048
#define WS_N      2049
#define WS_ESUM   4096                  // [128 dims][1024 codes] fp32, atomic target
#define WS_EHI    (WS_ESUM + DIM*NE)    // 256KB bf16 image (16 chunks x 16KB)
#define WS_ET     (WS_EHI + 65536)      // [1024][128] fp32 transposed embed
#define WS_BUCKET (WS_ET + DIM*NE)      // 65536 ints: row ids grouped by code
#define WS_OFF    (WS_BUCKET + N_ROWS)  // 1024 ints
#define WS_POS    (WS_OFF + 1024)       // 1024 ints
#define WS_ZERO_BYTES ((WS_ESUM + DIM*NE) * 4)

// out float offsets (reference return order)
#define O_Q    0
#define O_IND  (N_ROWS*DIM)
#define O_LOSS (O_IND + N_ROWS)
#define O_ENEW (O_LOSS + 1)
#define O_CS   (O_ENEW + DIM*NE)
#define O_EAVG (O_CS + NE)

__device__ __forceinline__ unsigned short f2bf(float f) {
    unsigned u = __float_as_uint(f);
    unsigned r = (u + 0x7fffu + ((u >> 16) & 1u)) >> 16;
    return (unsigned short)r;
}
__device__ __forceinline__ void stage16(const void* g, void* l) {
    __builtin_amdgcn_global_load_lds(
        (const __attribute__((address_space(1))) unsigned*)g,
        (__attribute__((address_space(3))) unsigned*)l, 16, 0, 0);
}

// Image layout (per 64-code chunk, 16KB): byte = c*256 + ((k*2) ^ ((c&15)<<4)),
// i.e. 16B slot s of code-row c holds k = (s^(c&15))*8 .. +7.
// Grid 64: block = (chunk b = bx>>2, k-quarter kq = bx&3).
__global__ __launch_bounds__(256) void k_prep(const float* __restrict__ E,
                                              float* __restrict__ ws) {
    __shared__ float ls[64][33];        // [c][k-local], padded
    __shared__ float part[4][64];
    const int tid = threadIdx.x;
    const int b = blockIdx.x >> 2, kq = blockIdx.x & 3;
    const int lane = tid & 63, wid = tid >> 6;

    float sq = 0.f;
    #pragma unroll
    for (int t = 0; t < 8; ++t) {       // k-local = 4t+wid, c = lane (coalesced)
        int kk = t * 4 + wid;
        float v = E[(kq * 32 + kk) * NE + b * 64 + lane];
        ls[lane][kk] = v;
        sq += v * v;
    }
    part[wid][lane] = sq;
    __syncthreads();
    if (tid < 64)
        atomicAdd(ws + WS_ESQ + b * 64 + tid,
                  part[0][tid] + part[1][tid] + part[2][tid] + part[3][tid]);

    {   // bf16 image: 256 16B-slots for this (chunk, k-quarter)
        int c = tid >> 2, u = tid & 3;
        int kk8 = kq * 4 + u;           // global k/8
        int slot = kk8 ^ (c & 15);
        short8 hv;
        #pragma unroll
        for (int e = 0; e < 8; ++e)
            hv[e] = (short)f2bf(ls[c][u * 8 + e]);
        *(short8*)((char*)(ws + WS_EHI) + (size_t)b * 16384 + c * 256 + slot * 16) = hv;
    }
    float* et = ws + WS_ET;
    #pragma unroll
    for (int t = 0; t < 2; ++t) {       // E^T: 512 float4 per block
        int i = tid + t * 256;
        int c = i >> 3, k4i = i & 7;
        float4 v;
        v.x = ls[c][k4i * 4 + 0];
        v.y = ls[c][k4i * 4 + 1];
        v.z = ls[c][k4i * 4 + 2];
        v.w = ls[c][k4i * 4 + 3];
        *(float4*)(et + (size_t)(b * 64 + c) * DIM + kq * 32 + k4i * 4) = v;
    }
}

// 512 threads = 8 waves, 128 rows/block. Code-split: waves 0-3 scan chunks
// 0-7 (codes 0-511), waves 4-7 scan chunks 8-15 (codes 512-1023), same rows.
// Each group double-buffers its own 16KB chunk; argmin merged via LDS.
// dist_j = ||e_j||^2 - 2*(xh.eh)  (single-pass bf16).
__global__ __launch_bounds__(512, 4) void k_main(const float* __restrict__ X,
                                                 float* __restrict__ ws,
                                                 float* __restrict__ out) {
    __shared__ __align__(16) char es[2][2][16384];  // [group][buf][chunk image]
    __shared__ __align__(16) float esq_lds[NE];
    __shared__ int ind_sh[128];
    __shared__ float mbd[128];
    __shared__ int mbi[128];
    __shared__ float red2[8];

    const int tid = threadIdx.x;
    const int lane = tid & 63;
    const int wid = tid >> 6;           // 0..7
    const int grp = wid >> 2;           // 0 or 1
    const int rw = wid & 3;             // row-tile within block
    const int col0 = lane & 31;
    const int hi = lane >> 5;
    const int tig = tid & 255;          // thread id within group
    const int rowBase = blockIdx.x * 128;

    const char* ehiB = (const char*)(ws + WS_EHI);
    const char* grpB = ehiB + grp * 8 * 16384;   // group's 8-chunk region

    // stage group's chunk 0 (async DMA) before A-frag work
    #pragma unroll
    for (int t = 0; t < 4; ++t) {
        int i = tig + t * 256;
        stage16(grpB + i * 16, &es[grp][0][i * 16]);
    }

    if (tid < 256) ((float4*)esq_lds)[tid] = ((const float4*)(ws + WS_ESQ))[tid];

    // ---- A fragments in registers: row = lane&31, k = ks*16 + (lane>>5)*8 + e
    short8 ah[8];
    {
        const float* xr = X + (size_t)(rowBase + rw * 32 + col0) * DIM + hi * 8;
        #pragma unroll
        for (int ks = 0; ks < 8; ++ks) {
            float4 a = *(const float4*)(xr + ks * 16);
            float4 b = *(const float4*)(xr + ks * 16 + 4);
            short8 h;
            h[0] = (short)f2bf(a.x); h[1] = (short)f2bf(a.y);
            h[2] = (short)f2bf(a.z); h[3] = (short)f2bf(a.w);
            h[4] = (short)f2bf(b.x); h[5] = (short)f2bf(b.y);
            h[6] = (short)f2bf(b.z); h[7] = (short)f2bf(b.w);
            ah[ks] = h;
        }
    }
    __syncthreads();

    float bd[16];
    int bi[16];
    #pragma unroll
    for (int s = 0; s < 16; ++s) { bd[s] = 1e30f; bi[s] = 0; }

    const int swz = (col0 & 15) << 4;
    const int coff = col0 * 256;
    const int khb = hi * 16;

    for (int c = 0; c < 8; ++c) {
        const int cur = c & 1;
        if (c < 7) {                     // async prefetch group's next chunk
            const char* hp = grpB + (c + 1) * 16384;
            #pragma unroll
            for (int t = 0; t < 4; ++t) {
                int i = tig + t * 256;
                stage16(hp + i * 16, &es[grp][cur ^ 1][i * 16]);
            }
        }

        f32x16 h0, h1;                   // 2 independent accumulate chains
        #pragma unroll
        for (int s = 0; s < 16; ++s) { h0[s] = 0.f; h1[s] = 0.f; }

        const char* hb = es[grp][cur];
        __builtin_amdgcn_s_setprio(1);
        #pragma unroll
        for (int ks = 0; ks < 8; ++ks) {
            int kb = (ks * 32 + khb) ^ swz;
            short8 bh0 = *(const short8*)(hb + coff + kb);
            short8 bh1 = *(const short8*)(hb + 8192 + coff + kb);
            h0 = __builtin_amdgcn_mfma_f32_32x32x16_bf16(ah[ks], bh0, h0, 0, 0, 0);
            h1 = __builtin_amdgcn_mfma_f32_32x32x16_bf16(ah[ks], bh1, h1, 0, 0, 0);
        }
        __builtin_amdgcn_s_setprio(0);

        // dist + running argmin. C: col=lane&31, row=(r&3)+8*(r>>2)+4*(lane>>5)
        int base = (grp * 8 + c) * 64;
        float e0 = esq_lds[base + col0];
        float e1 = esq_lds[base + 32 + col0];
        int c0 = base + col0, c1 = base + 32 + col0;
        #pragma unroll
        for (int r = 0; r < 16; ++r) {
            float s0 = e0 - 2.f * h0[r];
            if (s0 < bd[r]) { bd[r] = s0; bi[r] = c0; }
            float s1 = e1 - 2.f * h1[r];
            if (s1 < bd[r]) { bd[r] = s1; bi[r] = c1; }
        }
        __syncthreads();
    }

    // ---- argmin across the 32 col-lanes (tie-break: smaller index) ----
    #pragma unroll
    for (int r = 0; r < 16; ++r) {
        #pragma unroll
        for (int off = 1; off < 32; off <<= 1) {
            float od = __shfl_xor(bd[r], off, 64);
            int oi = __shfl_xor(bi[r], off, 64);
            if (od < bd[r] || (od == bd[r] && oi < bi[r])) { bd[r] = od; bi[r] = oi; }
        }
    }
    // ---- merge the two code-groups (group1 codes all larger: strict <) ----
    if (grp == 1 && col0 == 0) {
        #pragma unroll
        for (int r = 0; r < 16; ++r) {
            int row = rw * 32 + (r & 3) + 8 * (r >> 2) + 4 * hi;
            mbd[row] = bd[r];
            mbi[row] = bi[r];
        }
    }
    __syncthreads();
    if (grp == 0 && col0 == 0) {
        int* cnt = (int*)(ws + WS_CNTI);
        #pragma unroll
        for (int r = 0; r < 16; ++r) {
            int row = rw * 32 + (r & 3) + 8 * (r >> 2) + 4 * hi;
            float od = mbd[row];
            int b = (od < bd[r]) ? mbi[row] : bi[r];
            ind_sh[row] = b;
            out[O_IND + rowBase + row] = (float)b;
            atomicAdd(&cnt[b], 1);
        }
    }
    __syncthreads();

    // ---- quantize + ST + loss: contiguous full-line writes ----
    float lp = 0.f;
    {
        const float* et = ws + WS_ET;
        int rsub = tid >> 5;            // 0..15
        int d4 = (tid & 31) * 4;
        #pragma unroll
        for (int seg = 0; seg < 8; ++seg) {
            int row = seg * 16 + rsub;
            int j = ind_sh[row];
            float4 xv = *(const float4*)(X + (size_t)(rowBase + row) * DIM + d4);
            float4 qv = *(const float4*)(et + (size_t)j * DIM + d4);
            float4 st;
            st.x = xv.x + (qv.x - xv.x);
            st.y = xv.y + (qv.y - xv.y);
            st.z = xv.z + (qv.z - xv.z);
            st.w = xv.w + (qv.w - xv.w);
            *(float4*)(out + O_Q + (size_t)(rowBase + row) * DIM + d4) = st;
            float dx;
            dx = qv.x - xv.x; lp += dx * dx;
            dx = qv.y - xv.y; lp += dx * dx;
            dx = qv.z - xv.z; lp += dx * dx;
            dx = qv.w - xv.w; lp += dx * dx;
        }
    }
    #pragma unroll
    for (int off = 32; off; off >>= 1) lp += __shfl_down(lp, off, 64);
    if (lane == 0) red2[wid] = lp;
    __syncthreads();
    if (tid == 0) {
        float t = 0.f;
        #pragma unroll
        for (int w = 0; w < 8; ++w) t += red2[w];
        atomicAdd(ws + WS_LOSS, t);
    }
}

// 1 block, 1024 threads: off=excl_scan(cnt), pos=0, n=sum(csn), CS_new, loss.
__global__ __launch_bounds__(1024) void k_scan(const float* __restrict__ CS,
                                               float* __restrict__ ws,
                                               float* __restrict__ out) {
    __shared__ int wsum[16];
    __shared__ float fsum[16];
    int tid = threadIdx.x;
    int* cnt = (int*)(ws + WS_CNTI);
    int v = cnt[tid];
    float csn = 0.99f * CS[tid] + 0.01f * (float)v;
    out[O_CS + tid] = csn;
    float s = csn;
    #pragma unroll
    for (int off = 32; off; off >>= 1) s += __shfl_down(s, off, 64);
    int sc = v;
    #pragma unroll
    for (int d = 1; d < 64; d <<= 1) {
        int t = __shfl_up(sc, d, 64);
        if ((tid & 63) >= d) sc += t;
    }
    if ((tid & 63) == 0) fsum[tid >> 6] = s;
    if ((tid & 63) == 63) wsum[tid >> 6] = sc;
    __syncthreads();
    if (tid == 0) {
        int run = 0;
        float n = 0.f;
        for (int w = 0; w < 16; ++w) {
            int t = wsum[w]; wsum[w] = run; run += t;
            n += fsum[w];
        }
        ws[WS_N] = n;
        out[O_LOSS] = ws[WS_LOSS] * (1.0f / ((float)N_ROWS * (float)DIM));
    }
    __syncthreads();
    ((int*)(ws + WS_OFF))[tid] = sc - v + wsum[tid >> 6];
    ((int*)(ws + WS_POS))[tid] = 0;
}

// one thread per row: claim slot, write row id into its code's bucket.
__global__ __launch_bounds__(256) void k_scatter(const float* __restrict__ out,
                                                 float* __restrict__ ws) {
    int i = blockIdx.x * 256 + threadIdx.x;
    int j = (int)out[O_IND + i];
    int* pos = (int*)(ws + WS_POS);
    int slot = atomicAdd(&pos[j], 1);
    ((int*)(ws + WS_BUCKET))[((int*)(ws + WS_OFF))[j] + slot] = i;
}

// Position-parallel ordered segment-sum: block b owns bucket positions
// [b*64, b*64+64); thread = dim d. One atomic flush per (dim, code-run).
__global__ __launch_bounds__(128) void k_segsum(const float* __restrict__ X,
                                                float* __restrict__ ws) {
    __shared__ int offL[1025];
    __shared__ int rs[64];
    const int tid = threadIdx.x;
    const int p0 = blockIdx.x * 64;
    const int* off = (const int*)(ws + WS_OFF);
    #pragma unroll
    for (int t = 0; t < 8; ++t) offL[tid + t * 128] = off[tid + t * 128];
    if (tid == 0) offL[1024] = N_ROWS;
    if (tid < 64) rs[tid] = ((const int*)(ws + WS_BUCKET))[p0 + tid];
    __syncthreads();

    int lo = 0, hi2 = 1023;             // largest j with offL[j] <= p0
    while (lo < hi2) {
        int mid = (lo + hi2 + 1) >> 1;
        if (offL[mid] <= p0) lo = mid; else hi2 = mid - 1;
    }
    int j = lo;
    int bnd = offL[j + 1];
    float* esum = ws + WS_ESUM;
    float acc = 0.f;
    #pragma unroll 2
    for (int base = 0; base < 64; base += 8) {
        float v[8];
        #pragma unroll
        for (int u = 0; u < 8; ++u)
            v[u] = X[(size_t)rs[base + u] * DIM + tid];
        #pragma unroll
        for (int u = 0; u < 8; ++u) {
            int p = p0 + base + u;
            if (p >= bnd) {
                atomicAdd(&esum[tid * NE + j], acc);
                acc = 0.f;
                do { ++j; bnd = offL[j + 1]; } while (p >= bnd);
            }
            acc += v[u];
        }
    }
    atomicAdd(&esum[tid * NE + j], acc);
}

// EMA update / normalize; fully coalesced over codes j.
__global__ __launch_bounds__(256) void k_final(const float* __restrict__ CS,
                                               const float* __restrict__ EA,
                                               const float* __restrict__ ws,
                                               float* __restrict__ out) {
    int d = blockIdx.x >> 2;
    int j = (blockIdx.x & 3) * 256 + threadIdx.x;
    float nall = ws[WS_N];
    float csn = 0.99f * CS[j] + 0.01f * (float)((const int*)(ws + WS_CNTI))[j];
    float cs = (csn + 1e-5f) / (nall + (float)NE * 1e-5f) * nall;
    float ean = EA[(size_t)d * NE + j] * 0.99f + 0.01f * ws[WS_ESUM + (size_t)d * NE + j];
    out[O_EAVG + (size_t)d * NE + j] = ean;
    out[O_ENEW + (size_t)d * NE + j] = ean / cs;
}

extern "C" void kernel_launch(void* const* d_in, const int* in_sizes, int n_in,
                              void* d_out, int out_size, void* d_ws, size_t ws_size,
                              hipStream_t stream) {
    const float* X = (const float*)d_in[0];    // inputs  [16,64,64,128]
    const float* E = (const float*)d_in[1];    // embed   [128,1024]
    const float* CS = (const float*)d_in[2];   // cluster_size [1024]
    const float* EA = (const float*)d_in[3];   // embed_avg    [128,1024]
    float* out = (float*)d_out;
    float* ws = (float*)d_ws;

    hipMemsetAsync(d_ws, 0, (size_t)WS_ZERO_BYTES, stream);
    k_prep   <<<dim3(64),           dim3(256),  0, stream>>>(E, ws);
    k_main   <<<dim3(N_ROWS / 128), dim3(512),  0, stream>>>(X, ws, out);
    k_scan   <<<dim3(1),            dim3(1024), 0, stream>>>(CS, ws, out);
    k_scatter<<<dim3(N_ROWS / 256), dim3(256),  0, stream>>>(out, ws);
    k_segsum <<<dim3(N_ROWS / 64),  dim3(128),  0, stream>>>(X, ws);
    k_final  <<<dim3(512),          dim3(256),  0, stream>>>(CS, EA, ws, out);
}